// Round 1
// baseline (994.051 us; speedup 1.0000x reference)
//
#include <hip/hip_runtime.h>

// ---------------- problem config ----------------
constexpr int CB = 4, CN = 4096, CD = 1024, CH = 16, CDH = 64, CGH = 256, CFREQ = 2049, CBH = 64;

// ---------------- workspace layout (float offsets) ----------------
constexpr size_t OFF_XSUM = 0;                                   // 4096
constexpr size_t OFF_HG   = 4096;                                // 64*256
constexpr size_t OFF_HW   = OFF_HG + (size_t)CBH * CGH;          // 20480
constexpr size_t OFF_GATE = OFF_HW + (size_t)CBH * CGH;          // 36864, 64*4098 floats (interleaved complex)
constexpr size_t OFF_S    = OFF_GATE + (size_t)CBH * 2 * CFREQ;  // 299136, 64*4096
constexpr size_t OFF_CA   = OFF_S + (size_t)CBH * CN;            // 561280, 64*2048
constexpr size_t OFF_CD   = OFF_CA + (size_t)CBH * (CN / 2);     // 692352, 64*2048
constexpr size_t OFF_TW   = OFF_CD + (size_t)CBH * (CN / 2);     // 823424, 2048 float2
constexpr size_t OFF_VCOL = OFF_TW + 4096;                       // 827520, 4*1024*4096 (layout [b][d][n])
// total = 17,604,736 floats = 70.4 MB

__device__ __forceinline__ float silu_f(float x) { return x / (1.0f + expf(-x)); }

// ---------------- twiddle table: tw[i] = exp(-2*pi*i*i/4096), i in [0,2048) ----------------
__global__ void k_tw(float* twf) {
    int i = blockIdx.x * 256 + threadIdx.x;
    if (i < 2048) {
        double ang = -2.0 * 3.14159265358979323846 * (double)i / 4096.0;
        twf[2 * i]     = (float)cos(ang);
        twf[2 * i + 1] = (float)sin(ang);
    }
}

// ---------------- column sums of x over N (xsum[b][d] = sum_n x[b,n,d]) ----------------
__global__ __launch_bounds__(256) void k_mean(const float* __restrict__ X, float* __restrict__ xsum) {
    int b = blockIdx.y;          // 0..3
    int c = blockIdx.x;          // 0..63 (64-row chunk)
    int t = threadIdx.x;         // 0..255 -> d = 4t..4t+3
    const float* base = X + (size_t)b * CN * CD + (size_t)c * 64 * CD + t * 4;
    float4 acc = make_float4(0.f, 0.f, 0.f, 0.f);
    for (int n = 0; n < 64; ++n) {
        float4 v = *(const float4*)(base + (size_t)n * CD);
        acc.x += v.x; acc.y += v.y; acc.z += v.z; acc.w += v.w;
    }
    atomicAdd(&xsum[b * CD + 4 * t + 0], acc.x);
    atomicAdd(&xsum[b * CD + 4 * t + 1], acc.y);
    atomicAdd(&xsum[b * CD + 4 * t + 2], acc.z);
    atomicAdd(&xsum[b * CD + 4 * t + 3], acc.w);
}

// ---------------- bar = LN(mean_n q) ; hidden_g/hidden_w = silu(bar @ W*up.T) ----------------
__global__ __launch_bounds__(256) void k_barhidden(const float* __restrict__ xsum,
                                                   const float* __restrict__ Wq,
                                                   const float* __restrict__ ln_g,
                                                   const float* __restrict__ ln_b,
                                                   const float* __restrict__ Wgup,
                                                   const float* __restrict__ Wwup,
                                                   float* __restrict__ hg, float* __restrict__ hw) {
    int bh = blockIdx.x;      // b*16+h
    int b = bh >> 4, h = bh & 15;
    int t = threadIdx.x;
    __shared__ float part[256];
    __shared__ float bar_s[64];

    // qbar[dh] = (1/N) * sum_d Wq[h*64+dh, d] * xsum[b, d]
    int dh = t >> 2, seg = t & 3;
    const float* wrow = Wq + (size_t)(h * 64 + dh) * CD + seg * 256;
    const float* xs = xsum + b * CD + seg * 256;
    float acc = 0.f;
    for (int i = 0; i < 256; i += 4) {
        float4 w4 = *(const float4*)(wrow + i);
        float4 x4 = *(const float4*)(xs + i);
        acc += w4.x * x4.x + w4.y * x4.y + w4.z * x4.z + w4.w * x4.w;
    }
    part[t] = acc;
    __syncthreads();
    if (t < 64) {
        float q = (part[4 * t] + part[4 * t + 1] + part[4 * t + 2] + part[4 * t + 3]) * (1.0f / 4096.0f);
        float mu = q;
        for (int o = 32; o >= 1; o >>= 1) mu += __shfl_xor(mu, o, 64);
        mu *= (1.0f / 64.0f);
        float dev = q - mu;
        float vv = dev * dev;
        for (int o = 32; o >= 1; o >>= 1) vv += __shfl_xor(vv, o, 64);
        vv *= (1.0f / 64.0f);
        bar_s[t] = dev / sqrtf(vv + 1e-6f) * ln_g[t] + ln_b[t];
    }
    __syncthreads();
    // hidden (one output per thread, GH=256)
    const float* gup = Wgup + (size_t)t * CDH;
    const float* wup = Wwup + (size_t)t * CDH;
    float ag = 0.f, aw = 0.f;
    for (int i = 0; i < CDH; i += 4) {
        float4 bb = *(const float4*)(&bar_s[i]);
        float4 g4 = *(const float4*)(gup + i);
        float4 w4 = *(const float4*)(wup + i);
        ag += g4.x * bb.x + g4.y * bb.y + g4.z * bb.z + g4.w * bb.w;
        aw += w4.x * bb.x + w4.y * bb.y + w4.z * bb.z + w4.w * bb.w;
    }
    hg[bh * CGH + t] = silu_f(ag);
    hw[bh * CGH + t] = silu_f(aw);
}

// ---------------- gr = hidden_g @ Wgdn.T (4098 out) ; s = hidden_w @ Wwdn.T (4096 out) ----------------
// grid: (17 chunks, 8 bh-groups, 2 types); weight rows streamed per lane, hidden broadcast from LDS.
__global__ __launch_bounds__(256) void k_gategemv(const float* __restrict__ Wgdn,
                                                  const float* __restrict__ Wwdn,
                                                  const float* __restrict__ hg,
                                                  const float* __restrict__ hw,
                                                  float* __restrict__ gate, float* __restrict__ sbuf) {
    int z = blockIdx.z;
    const float* Wd = z ? Wwdn : Wgdn;
    const float* hid = z ? hw : hg;
    float* out = z ? sbuf : gate;
    int Kout = z ? CN : 2 * CFREQ;
    int bh0 = blockIdx.y * 8;
    int t = threadIdx.x;
    int k = blockIdx.x * 256 + t;
    __shared__ float Lh[8][256];
    for (int g = 0; g < 8; ++g) Lh[g][t] = hid[(size_t)(bh0 + g) * CGH + t];
    __syncthreads();
    if (k >= Kout) return;
    float accv[8] = {0.f, 0.f, 0.f, 0.f, 0.f, 0.f, 0.f, 0.f};
    const float* wrow = Wd + (size_t)k * CGH;
    for (int j4 = 0; j4 < 64; ++j4) {
        float4 wv = *(const float4*)(wrow + 4 * j4);
#pragma unroll
        for (int g = 0; g < 8; ++g) {
            accv[g] += wv.x * Lh[g][4 * j4] + wv.y * Lh[g][4 * j4 + 1] +
                       wv.z * Lh[g][4 * j4 + 2] + wv.w * Lh[g][4 * j4 + 3];
        }
    }
    for (int g = 0; g < 8; ++g) out[(size_t)(bh0 + g) * Kout + k] = accv[g];
}

// ---------------- mixing coefficients: ca = 1 + (s_i + s_{i+2048})/2 ; cd = (s_i - s_{i+2048})/2 ----------------
__global__ __launch_bounds__(256) void k_coef(const float* __restrict__ sbuf,
                                              float* __restrict__ ca, float* __restrict__ cd) {
    int bh = blockIdx.y;
    int i = blockIdx.x * 256 + threadIdx.x;   // 0..2047
    float s0 = sbuf[(size_t)bh * CN + i];
    float s1 = sbuf[(size_t)bh * CN + 2048 + i];
    ca[(size_t)bh * 2048 + i] = 1.0f + 0.5f * (s0 + s1);
    cd[(size_t)bh * 2048 + i] = 0.5f * (s0 - s1);
}

// ---------------- GEMM1: Vcol[b*1024+d'][n] = sum_k x[b,n,k] * Wv[d',k]  (NT, transposed store) ----------------
__global__ __launch_bounds__(256) void k_gemm_xw(const float* __restrict__ X,
                                                 const float* __restrict__ Wv,
                                                 float* __restrict__ Vcol) {
    __shared__ float As[16][132];
    __shared__ float Ws[16][132];
    int t = threadIdx.x;
    int m0 = blockIdx.y * 128;      // global row (b*4096+n)
    int d0 = blockIdx.x * 128;
    int b = m0 >> 12, n0 = m0 & 4095;
    int tm = t & 15, td = t >> 4;   // lanes along m (for transposed-store coalescing)
    int r0 = t >> 2, c0 = (t & 3) * 4;
    float acc[8][8];
#pragma unroll
    for (int i = 0; i < 8; ++i)
#pragma unroll
        for (int j = 0; j < 8; ++j) acc[i][j] = 0.f;

    for (int k0 = 0; k0 < CD; k0 += 16) {
        float4 a0 = *(const float4*)(X + (size_t)(m0 + r0) * CD + k0 + c0);
        float4 a1 = *(const float4*)(X + (size_t)(m0 + r0 + 64) * CD + k0 + c0);
        float4 w0 = *(const float4*)(Wv + (size_t)(d0 + r0) * CD + k0 + c0);
        float4 w1 = *(const float4*)(Wv + (size_t)(d0 + r0 + 64) * CD + k0 + c0);
        __syncthreads();
        As[c0 + 0][r0] = a0.x; As[c0 + 1][r0] = a0.y; As[c0 + 2][r0] = a0.z; As[c0 + 3][r0] = a0.w;
        As[c0 + 0][r0 + 64] = a1.x; As[c0 + 1][r0 + 64] = a1.y; As[c0 + 2][r0 + 64] = a1.z; As[c0 + 3][r0 + 64] = a1.w;
        Ws[c0 + 0][r0] = w0.x; Ws[c0 + 1][r0] = w0.y; Ws[c0 + 2][r0] = w0.z; Ws[c0 + 3][r0] = w0.w;
        Ws[c0 + 0][r0 + 64] = w1.x; Ws[c0 + 1][r0 + 64] = w1.y; Ws[c0 + 2][r0 + 64] = w1.z; Ws[c0 + 3][r0 + 64] = w1.w;
        __syncthreads();
#pragma unroll
        for (int k = 0; k < 16; ++k) {
            float av[8], wv[8];
            *(float4*)(av)     = *(const float4*)&As[k][tm * 8];
            *(float4*)(av + 4) = *(const float4*)&As[k][tm * 8 + 4];
            *(float4*)(wv)     = *(const float4*)&Ws[k][td * 8];
            *(float4*)(wv + 4) = *(const float4*)&Ws[k][td * 8 + 4];
#pragma unroll
            for (int i = 0; i < 8; ++i)
#pragma unroll
                for (int j = 0; j < 8; ++j) acc[i][j] += av[i] * wv[j];
        }
    }
#pragma unroll
    for (int j = 0; j < 8; ++j) {
        int dcol = d0 + td * 8 + j;
        float* dst = Vcol + (size_t)(b * CD + dcol) * CN + n0 + tm * 8;
        *(float4*)dst       = make_float4(acc[0][j], acc[1][j], acc[2][j], acc[3][j]);
        *(float4*)(dst + 4) = make_float4(acc[4][j], acc[5][j], acc[6][j], acc[7][j]);
    }
}

// ---------------- FFT chain: per block one (b,h) and one pair of DH-columns ----------------
// forward C2C FFT of packed pair -> hermitian unpack -> gate -> repack -> inverse FFT -> 2x2 pair mix
__global__ __launch_bounds__(256) void k_fft(float* __restrict__ Vcol,
                                             const float* __restrict__ gateB,
                                             const float* __restrict__ caB,
                                             const float* __restrict__ cdB,
                                             const float2* __restrict__ tw) {
    __shared__ float2 bufA[4096];
    __shared__ float2 bufB[4096];
    int blk = blockIdx.x;
    int bh = blk >> 5, pr = blk & 31;
    int t = threadIdx.x;
    float* colA = Vcol + (size_t)(bh * 64 + pr * 2) * CN;
    float* colB = colA + CN;

    for (int n = t; n < 4096; n += 256) bufA[n] = make_float2(colA[n], colB[n]);
    __syncthreads();

    float2* src = bufA;
    float2* dst = bufB;
    // forward FFT (sign -1), Stockham radix-2 DIF, natural order in/out
    for (int kst = 0; kst < 12; ++kst) {
        int s = 1 << kst;
        int m = 2048 >> kst;
        for (int idx = t; idx < 2048; idx += 256) {
            int p = idx >> kst;
            int q = idx & (s - 1);
            float2 a = src[q + (p << kst)];
            float2 bb = src[q + ((p + m) << kst)];
            float2 w = tw[p << kst];
            float2 sum = make_float2(a.x + bb.x, a.y + bb.y);
            float2 dif = make_float2(a.x - bb.x, a.y - bb.y);
            float2 wd = make_float2(dif.x * w.x - dif.y * w.y, dif.x * w.y + dif.y * w.x);
            dst[q + (p << (kst + 1))] = sum;
            dst[q + (p << (kst + 1)) + s] = wd;
        }
        __syncthreads();
        float2* tmp = src; src = dst; dst = tmp;
    }
    // src now holds Z[k]. Hermitian unpack, gate, repack W = SA + i*SB into dst.
    const float2* g2 = (const float2*)gateB + (size_t)bh * CFREQ;
    for (int kf = t; kf < 4096; kf += 256) {
        int j = (4096 - kf) & 4095;
        float2 Zk = src[kf], Zj = src[j];
        float2 Av = make_float2(0.5f * (Zk.x + Zj.x), 0.5f * (Zk.y - Zj.y));
        float2 Bv = make_float2(0.5f * (Zk.y + Zj.y), -0.5f * (Zk.x - Zj.x));
        float2 g;
        if (kf <= 2048) g = g2[kf];
        else { float2 gg = g2[4096 - kf]; g = make_float2(gg.x, -gg.y); }
        float2 SA = make_float2(g.x * Av.x - g.y * Av.y, g.x * Av.y + g.y * Av.x);
        float2 SB = make_float2(g.x * Bv.x - g.y * Bv.y, g.x * Bv.y + g.y * Bv.x);
        dst[kf] = make_float2(SA.x - SB.y, SA.y + SB.x);
    }
    __syncthreads();
    { float2* tmp = src; src = dst; dst = tmp; }
    // inverse FFT (sign +1): conjugated twiddles; unnormalized (1/N applied at epilogue)
    for (int kst = 0; kst < 12; ++kst) {
        int s = 1 << kst;
        int m = 2048 >> kst;
        for (int idx = t; idx < 2048; idx += 256) {
            int p = idx >> kst;
            int q = idx & (s - 1);
            float2 a = src[q + (p << kst)];
            float2 bb = src[q + ((p + m) << kst)];
            float2 w = tw[p << kst];
            float2 sum = make_float2(a.x + bb.x, a.y + bb.y);
            float2 dif = make_float2(a.x - bb.x, a.y - bb.y);
            float2 wd = make_float2(dif.x * w.x + dif.y * w.y, -dif.x * w.y + dif.y * w.x);
            dst[q + (p << (kst + 1))] = sum;
            dst[q + (p << (kst + 1)) + s] = wd;
        }
        __syncthreads();
        float2* tmp = src; src = dst; dst = tmp;
    }
    // src holds N * (v_t pair). Apply 1/N and the 2x2 adjacent mix, store back in place.
    const float scale = 1.0f / 4096.0f;
    const float* ca = caB + (size_t)bh * 2048;
    const float* cd = cdB + (size_t)bh * 2048;
    for (int i = t; i < 2048; i += 256) {
        float2 v0 = src[2 * i], v1 = src[2 * i + 1];
        float a0x = v0.x * scale, a1x = v1.x * scale;
        float a0y = v0.y * scale, a1y = v1.y * scale;
        float A_ = ca[i], D_ = cd[i];
        *(float2*)(colA + 2 * i) = make_float2(A_ * a0x + D_ * a1x, D_ * a0x + A_ * a1x);
        *(float2*)(colB + 2 * i) = make_float2(A_ * a0y + D_ * a1y, D_ * a0y + A_ * a1y);
    }
}

// ---------------- GEMM2: out[b,n,d'] = sum_k Vcol[b*1024+k][n] * Wo[d',k]  (TN) ----------------
__global__ __launch_bounds__(256) void k_gemm_out(const float* __restrict__ Vcol,
                                                  const float* __restrict__ Wo,
                                                  float* __restrict__ Out) {
    __shared__ float As[16][132];
    __shared__ float Ws[16][132];
    int t = threadIdx.x;
    int m0 = blockIdx.y * 128;
    int d0 = blockIdx.x * 128;
    int b = m0 >> 12, n0 = m0 & 4095;
    int kk = t >> 4;            // 0..15 (k within tile, for A staging)
    int mm = (t & 15) * 4;      // 0..60
    int r0 = t >> 2, c0 = (t & 3) * 4;  // for W staging
    int td = t & 15, tm = t >> 4;       // lanes along d' (row-major store coalescing)
    float acc[8][8];
#pragma unroll
    for (int i = 0; i < 8; ++i)
#pragma unroll
        for (int j = 0; j < 8; ++j) acc[i][j] = 0.f;

    for (int k0 = 0; k0 < CD; k0 += 16) {
        float4 a0 = *(const float4*)(Vcol + (size_t)(b * CD + k0 + kk) * CN + n0 + mm);
        float4 a1 = *(const float4*)(Vcol + (size_t)(b * CD + k0 + kk) * CN + n0 + mm + 64);
        float4 w0 = *(const float4*)(Wo + (size_t)(d0 + r0) * CD + k0 + c0);
        float4 w1 = *(const float4*)(Wo + (size_t)(d0 + r0 + 64) * CD + k0 + c0);
        __syncthreads();
        *(float4*)&As[kk][mm] = a0;
        *(float4*)&As[kk][mm + 64] = a1;
        Ws[c0 + 0][r0] = w0.x; Ws[c0 + 1][r0] = w0.y; Ws[c0 + 2][r0] = w0.z; Ws[c0 + 3][r0] = w0.w;
        Ws[c0 + 0][r0 + 64] = w1.x; Ws[c0 + 1][r0 + 64] = w1.y; Ws[c0 + 2][r0 + 64] = w1.z; Ws[c0 + 3][r0 + 64] = w1.w;
        __syncthreads();
#pragma unroll
        for (int k = 0; k < 16; ++k) {
            float av[8], wv[8];
            *(float4*)(av)     = *(const float4*)&As[k][tm * 8];
            *(float4*)(av + 4) = *(const float4*)&As[k][tm * 8 + 4];
            *(float4*)(wv)     = *(const float4*)&Ws[k][td * 8];
            *(float4*)(wv + 4) = *(const float4*)&Ws[k][td * 8 + 4];
#pragma unroll
            for (int i = 0; i < 8; ++i)
#pragma unroll
                for (int j = 0; j < 8; ++j) acc[i][j] += av[i] * wv[j];
        }
    }
#pragma unroll
    for (int i = 0; i < 8; ++i) {
        float* dstp = Out + (size_t)(m0 + tm * 8 + i) * CD + d0 + td * 8;
        *(float4*)dstp       = make_float4(acc[i][0], acc[i][1], acc[i][2], acc[i][3]);
        *(float4*)(dstp + 4) = make_float4(acc[i][4], acc[i][5], acc[i][6], acc[i][7]);
    }
}

// ---------------- launch ----------------
extern "C" void kernel_launch(void* const* d_in, const int* in_sizes, int n_in,
                              void* d_out, int out_size, void* d_ws, size_t ws_size,
                              hipStream_t stream) {
    const float* x    = (const float*)d_in[0];
    const float* Wq   = (const float*)d_in[1];
    const float* Wv   = (const float*)d_in[2];
    const float* Wo   = (const float*)d_in[3];
    const float* ln_g = (const float*)d_in[4];
    const float* ln_b = (const float*)d_in[5];
    const float* Wgup = (const float*)d_in[6];
    const float* Wgdn = (const float*)d_in[7];
    const float* Wwup = (const float*)d_in[8];
    const float* Wwdn = (const float*)d_in[9];
    float* ws  = (float*)d_ws;
    float* out = (float*)d_out;

    hipMemsetAsync(ws + OFF_XSUM, 0, 4096 * sizeof(float), stream);
    k_tw<<<8, 256, 0, stream>>>(ws + OFF_TW);
    k_mean<<<dim3(64, 4), 256, 0, stream>>>(x, ws + OFF_XSUM);
    k_barhidden<<<64, 256, 0, stream>>>(ws + OFF_XSUM, Wq, ln_g, ln_b, Wgup, Wwup,
                                        ws + OFF_HG, ws + OFF_HW);
    k_gategemv<<<dim3(17, 8, 2), 256, 0, stream>>>(Wgdn, Wwdn, ws + OFF_HG, ws + OFF_HW,
                                                   ws + OFF_GATE, ws + OFF_S);
    k_coef<<<dim3(8, 64), 256, 0, stream>>>(ws + OFF_S, ws + OFF_CA, ws + OFF_CD);
    k_gemm_xw<<<dim3(8, 128), 256, 0, stream>>>(x, Wv, ws + OFF_VCOL);
    k_fft<<<2048, 256, 0, stream>>>(ws + OFF_VCOL, ws + OFF_GATE, ws + OFF_CA, ws + OFF_CD,
                                    (const float2*)(ws + OFF_TW));
    k_gemm_out<<<dim3(8, 128), 256, 0, stream>>>(ws + OFF_VCOL, Wo, out);
}

// Round 2
// 530.982 us; speedup vs baseline: 1.8721x; 1.8721x over previous
//
#include <hip/hip_runtime.h>

// ---------------- problem config ----------------
constexpr int CB = 4, CN = 4096, CD = 1024, CH = 16, CDH = 64, CGH = 256, CFREQ = 2049, CBH = 64;

// ---------------- workspace layout (float offsets) ----------------
constexpr size_t OFF_XSUM = 0;                                   // 4096
constexpr size_t OFF_HG   = 4096;
constexpr size_t OFF_HW   = OFF_HG + (size_t)CBH * CGH;
constexpr size_t OFF_GATE = OFF_HW + (size_t)CBH * CGH;
constexpr size_t OFF_S    = OFF_GATE + (size_t)CBH * 2 * CFREQ;
constexpr size_t OFF_CA   = OFF_S + (size_t)CBH * CN;
constexpr size_t OFF_CD   = OFF_CA + (size_t)CBH * (CN / 2);
constexpr size_t OFF_TW   = OFF_CD + (size_t)CBH * (CN / 2);
constexpr size_t OFF_VCOL = OFF_TW + 4096;                       // fp32 [b][d][n], 16.78M
constexpr size_t OFF_XHI  = OFF_VCOL + (size_t)CB * CD * CN;     // bf16 planes (sizes in floats = half)
constexpr size_t OFF_XLO  = OFF_XHI + (size_t)CB * CN * CD / 2;
constexpr size_t OFF_WVHI = OFF_XLO + (size_t)CB * CN * CD / 2;
constexpr size_t OFF_WVLO = OFF_WVHI + (size_t)CD * CD / 2;
constexpr size_t OFF_WOHI = OFF_WVLO + (size_t)CD * CD / 2;
constexpr size_t OFF_WOLO = OFF_WOHI + (size_t)CD * CD / 2;
// V2 planes (v_t transposed split, for GEMM2) ALIAS the X planes: X is dead after GEMM1.
// total ws = OFF_WOLO + CD*CD/2 floats  ≈ 146 MB

typedef __bf16 bf16x8 __attribute__((ext_vector_type(8)));
typedef __bf16 bf16x4 __attribute__((ext_vector_type(4)));
typedef float  f32x4  __attribute__((ext_vector_type(4)));

__device__ __forceinline__ float silu_f(float x) { return x / (1.0f + expf(-x)); }

// async global->LDS, 16 B per lane (CK-style addrspace casts)
__device__ __forceinline__ void gload16(const void* g, void* l) {
    __builtin_amdgcn_global_load_lds(
        reinterpret_cast<const __attribute__((address_space(1))) unsigned int*>(
            reinterpret_cast<uintptr_t>(g)),
        reinterpret_cast<__attribute__((address_space(3))) unsigned int*>(
            reinterpret_cast<uintptr_t>(l)),
        16, 0, 0);
}

// ---------------- twiddle table ----------------
__global__ void k_tw(float* twf) {
    int i = blockIdx.x * 256 + threadIdx.x;
    if (i < 2048) {
        double ang = -2.0 * 3.14159265358979323846 * (double)i / 4096.0;
        twf[2 * i]     = (float)cos(ang);
        twf[2 * i + 1] = (float)sin(ang);
    }
}

// ---------------- column sums of x over N ----------------
__global__ __launch_bounds__(256) void k_mean(const float* __restrict__ X, float* __restrict__ xsum) {
    int b = blockIdx.y;
    int c = blockIdx.x;
    int t = threadIdx.x;
    const float* base = X + (size_t)b * CN * CD + (size_t)c * 64 * CD + t * 4;
    float4 acc = make_float4(0.f, 0.f, 0.f, 0.f);
    for (int n = 0; n < 64; ++n) {
        float4 v = *(const float4*)(base + (size_t)n * CD);
        acc.x += v.x; acc.y += v.y; acc.z += v.z; acc.w += v.w;
    }
    atomicAdd(&xsum[b * CD + 4 * t + 0], acc.x);
    atomicAdd(&xsum[b * CD + 4 * t + 1], acc.y);
    atomicAdd(&xsum[b * CD + 4 * t + 2], acc.z);
    atomicAdd(&xsum[b * CD + 4 * t + 3], acc.w);
}

// ---------------- bar = LN(mean_n q) ; hidden = silu(bar @ Wup.T) ----------------
__global__ __launch_bounds__(256) void k_barhidden(const float* __restrict__ xsum,
                                                   const float* __restrict__ Wq,
                                                   const float* __restrict__ ln_g,
                                                   const float* __restrict__ ln_b,
                                                   const float* __restrict__ Wgup,
                                                   const float* __restrict__ Wwup,
                                                   float* __restrict__ hg, float* __restrict__ hw) {
    int bh = blockIdx.x;
    int b = bh >> 4, h = bh & 15;
    int t = threadIdx.x;
    __shared__ float part[256];
    __shared__ float bar_s[64];
    int dh = t >> 2, seg = t & 3;
    const float* wrow = Wq + (size_t)(h * 64 + dh) * CD + seg * 256;
    const float* xs = xsum + b * CD + seg * 256;
    float acc = 0.f;
    for (int i = 0; i < 256; i += 4) {
        float4 w4 = *(const float4*)(wrow + i);
        float4 x4 = *(const float4*)(xs + i);
        acc += w4.x * x4.x + w4.y * x4.y + w4.z * x4.z + w4.w * x4.w;
    }
    part[t] = acc;
    __syncthreads();
    if (t < 64) {
        float q = (part[4 * t] + part[4 * t + 1] + part[4 * t + 2] + part[4 * t + 3]) * (1.0f / 4096.0f);
        float mu = q;
        for (int o = 32; o >= 1; o >>= 1) mu += __shfl_xor(mu, o, 64);
        mu *= (1.0f / 64.0f);
        float dev = q - mu;
        float vv = dev * dev;
        for (int o = 32; o >= 1; o >>= 1) vv += __shfl_xor(vv, o, 64);
        vv *= (1.0f / 64.0f);
        bar_s[t] = dev / sqrtf(vv + 1e-6f) * ln_g[t] + ln_b[t];
    }
    __syncthreads();
    const float* gup = Wgup + (size_t)t * CDH;
    const float* wup = Wwup + (size_t)t * CDH;
    float ag = 0.f, aw = 0.f;
    for (int i = 0; i < CDH; i += 4) {
        float4 bb = *(const float4*)(&bar_s[i]);
        float4 g4 = *(const float4*)(gup + i);
        float4 w4 = *(const float4*)(wup + i);
        ag += g4.x * bb.x + g4.y * bb.y + g4.z * bb.z + g4.w * bb.w;
        aw += w4.x * bb.x + w4.y * bb.y + w4.z * bb.z + w4.w * bb.w;
    }
    hg[bh * CGH + t] = silu_f(ag);
    hw[bh * CGH + t] = silu_f(aw);
}

// ---------------- gr / s GEMVs ----------------
__global__ __launch_bounds__(256) void k_gategemv(const float* __restrict__ Wgdn,
                                                  const float* __restrict__ Wwdn,
                                                  const float* __restrict__ hg,
                                                  const float* __restrict__ hw,
                                                  float* __restrict__ gate, float* __restrict__ sbuf) {
    int z = blockIdx.z;
    const float* Wd = z ? Wwdn : Wgdn;
    const float* hid = z ? hw : hg;
    float* out = z ? sbuf : gate;
    int Kout = z ? CN : 2 * CFREQ;
    int bh0 = blockIdx.y * 8;
    int t = threadIdx.x;
    int k = blockIdx.x * 256 + t;
    __shared__ float Lh[8][256];
    for (int g = 0; g < 8; ++g) Lh[g][t] = hid[(size_t)(bh0 + g) * CGH + t];
    __syncthreads();
    if (k >= Kout) return;
    float accv[8] = {0.f, 0.f, 0.f, 0.f, 0.f, 0.f, 0.f, 0.f};
    const float* wrow = Wd + (size_t)k * CGH;
    for (int j4 = 0; j4 < 64; ++j4) {
        float4 wv = *(const float4*)(wrow + 4 * j4);
#pragma unroll
        for (int g = 0; g < 8; ++g) {
            accv[g] += wv.x * Lh[g][4 * j4] + wv.y * Lh[g][4 * j4 + 1] +
                       wv.z * Lh[g][4 * j4 + 2] + wv.w * Lh[g][4 * j4 + 3];
        }
    }
    for (int g = 0; g < 8; ++g) out[(size_t)(bh0 + g) * Kout + k] = accv[g];
}

// ---------------- mixing coefficients ----------------
__global__ __launch_bounds__(256) void k_coef(const float* __restrict__ sbuf,
                                              float* __restrict__ ca, float* __restrict__ cd) {
    int bh = blockIdx.y;
    int i = blockIdx.x * 256 + threadIdx.x;
    float s0 = sbuf[(size_t)bh * CN + i];
    float s1 = sbuf[(size_t)bh * CN + 2048 + i];
    ca[(size_t)bh * 2048 + i] = 1.0f + 0.5f * (s0 + s1);
    cd[(size_t)bh * 2048 + i] = 0.5f * (s0 - s1);
}

// ---------------- fp32 -> (hi,lo) bf16 split, elementwise ----------------
__global__ __launch_bounds__(256) void k_split(const float* __restrict__ src,
                                               __bf16* __restrict__ hi, __bf16* __restrict__ lo,
                                               int n4) {
    int i = blockIdx.x * 256 + threadIdx.x;
    int stride = gridDim.x * 256;
    for (; i < n4; i += stride) {
        float4 v = ((const float4*)src)[i];
        __bf16 h0 = (__bf16)v.x, h1 = (__bf16)v.y, h2 = (__bf16)v.z, h3 = (__bf16)v.w;
        bf16x4 hv = {h0, h1, h2, h3};
        bf16x4 lv = {(__bf16)(v.x - (float)h0), (__bf16)(v.y - (float)h1),
                     (__bf16)(v.z - (float)h2), (__bf16)(v.w - (float)h3)};
        *(bf16x4*)&hi[4 * (size_t)i] = hv;
        *(bf16x4*)&lo[4 * (size_t)i] = lv;
    }
}

// ---------------- transpose + split: Vcol fp32 [b][d][n] -> V2 planes [b*n][d] ----------------
__global__ __launch_bounds__(256) void k_tsplit(const float* __restrict__ Vcol,
                                                __bf16* __restrict__ hi, __bf16* __restrict__ lo) {
    __shared__ float tile[32][33];
    int bx = blockIdx.x;   // n block (128)
    int by = blockIdx.y;   // d block (32)
    int b  = blockIdx.z;
    int t = threadIdx.x;
    int d = t >> 3, n4 = (t & 7) * 4;
    const float* src = Vcol + ((size_t)b * CD + by * 32 + d) * CN + bx * 32 + n4;
    float4 v = *(const float4*)src;
    tile[d][n4] = v.x; tile[d][n4 + 1] = v.y; tile[d][n4 + 2] = v.z; tile[d][n4 + 3] = v.w;
    __syncthreads();
    int n = t >> 3, d4 = (t & 7) * 4;
    size_t o = ((size_t)b * CN + bx * 32 + n) * CD + by * 32 + d4;
    float x0 = tile[d4][n], x1 = tile[d4 + 1][n], x2 = tile[d4 + 2][n], x3 = tile[d4 + 3][n];
    __bf16 h0 = (__bf16)x0, h1 = (__bf16)x1, h2 = (__bf16)x2, h3 = (__bf16)x3;
    bf16x4 hv = {h0, h1, h2, h3};
    bf16x4 lv = {(__bf16)(x0 - (float)h0), (__bf16)(x1 - (float)h1),
                 (__bf16)(x2 - (float)h2), (__bf16)(x3 - (float)h3)};
    *(bf16x4*)&hi[o] = hv;
    *(bf16x4*)&lo[o] = lv;
}

// ---------------- split-bf16 MFMA GEMM: C = A @ B.T (M x 1024) ----------------
// A planes: [M][1024] bf16 (hi/lo); B planes: [1024][1024] bf16 (hi/lo).
// TRANS=1: C[(b*1024 + ncol)*4096 + tok] (Vcol layout). TRANS=0: C[m*1024 + ncol] row-major.
// 128x128 tile, BK=32, 4 waves (2x2), 16x16x32 MFMA, 3-pass split.
// LDS planes row-major [128][32] bf16 with XOR slot swizzle: slot' = slot ^ ((row>>2)&3).
template <int TRANS>
__global__ __launch_bounds__(256) void k_mfma_gemm(const __bf16* __restrict__ Ahi,
                                                   const __bf16* __restrict__ Alo,
                                                   const __bf16* __restrict__ Bhi,
                                                   const __bf16* __restrict__ Blo,
                                                   float* __restrict__ C) {
    __shared__ __align__(16) __bf16 lds[4][128 * 32];   // 0:Ahi 1:Alo 2:Bhi 3:Blo
    int t = threadIdx.x;
    int l = t & 63, w = t >> 6;
    int m0 = blockIdx.y * 128;
    int n0 = blockIdx.x * 128;
    int wm = w >> 1, wn = w & 1;

    // staging: wave w stages plane w (8 chunks of 16 rows x 32 cols)
    const __bf16* gsrc = (w == 0) ? Ahi : (w == 1) ? Alo : (w == 2) ? Bhi : Blo;
    int gr0 = (w < 2) ? m0 : n0;
    unsigned o[8];
#pragma unroll
    for (int i = 0; i < 8; ++i) {
        int row = i * 16 + (l >> 2);
        unsigned slot = (unsigned)((l & 3) ^ ((row >> 2) & 3));
        o[i] = (unsigned)(gr0 + row) * 1024u + slot * 8u;
    }
    __bf16* ldsw = &lds[w][0];

    f32x4 acc[4][4];
#pragma unroll
    for (int m = 0; m < 4; ++m)
#pragma unroll
        for (int n = 0; n < 4; ++n) acc[m][n] = (f32x4){0.f, 0.f, 0.f, 0.f};

    for (int k0 = 0; k0 < 1024; k0 += 32) {
#pragma unroll
        for (int i = 0; i < 8; ++i)
            gload16(gsrc + ((size_t)o[i] + k0), ldsw + i * 512);
        __syncthreads();

        bf16x8 ah[4], al[4], bh[4], bl[4];
#pragma unroll
        for (int m = 0; m < 4; ++m) {
            int row = wm * 64 + m * 16 + (l & 15);
            int sl = (l >> 4) ^ ((row >> 2) & 3);
            ah[m] = *(const bf16x8*)&lds[0][row * 32 + sl * 8];
            al[m] = *(const bf16x8*)&lds[1][row * 32 + sl * 8];
        }
#pragma unroll
        for (int n = 0; n < 4; ++n) {
            int row = wn * 64 + n * 16 + (l & 15);
            int sl = (l >> 4) ^ ((row >> 2) & 3);
            bh[n] = *(const bf16x8*)&lds[2][row * 32 + sl * 8];
            bl[n] = *(const bf16x8*)&lds[3][row * 32 + sl * 8];
        }
#pragma unroll
        for (int m = 0; m < 4; ++m)
#pragma unroll
            for (int n = 0; n < 4; ++n) {
                acc[m][n] = __builtin_amdgcn_mfma_f32_16x16x32_bf16(ah[m], bh[n], acc[m][n], 0, 0, 0);
                acc[m][n] = __builtin_amdgcn_mfma_f32_16x16x32_bf16(ah[m], bl[n], acc[m][n], 0, 0, 0);
                acc[m][n] = __builtin_amdgcn_mfma_f32_16x16x32_bf16(al[m], bh[n], acc[m][n], 0, 0, 0);
            }
        __syncthreads();
    }

    // epilogue: C/D layout col = l&15, row = (l>>4)*4 + q  [m89/m91 verified]
    if (TRANS) {
        int b = m0 >> 12;
        int tokb = (m0 & 4095) + wm * 64;
#pragma unroll
        for (int m = 0; m < 4; ++m)
#pragma unroll
            for (int n = 0; n < 4; ++n) {
                int dcol = n0 + wn * 64 + n * 16 + (l & 15);
                int tok = tokb + m * 16 + ((l >> 4) << 2);
                *(f32x4*)&C[((size_t)(b * CD + dcol)) * CN + tok] = acc[m][n];
            }
    } else {
#pragma unroll
        for (int m = 0; m < 4; ++m)
#pragma unroll
            for (int n = 0; n < 4; ++n) {
                int r0 = m0 + wm * 64 + m * 16 + ((l >> 4) << 2);
                int cc = n0 + wn * 64 + n * 16 + (l & 15);
#pragma unroll
                for (int q = 0; q < 4; ++q) C[(size_t)(r0 + q) * CD + cc] = acc[m][n][q];
            }
    }
}

// ---------------- FFT chain (unchanged, verified) ----------------
__global__ __launch_bounds__(256) void k_fft(float* __restrict__ Vcol,
                                             const float* __restrict__ gateB,
                                             const float* __restrict__ caB,
                                             const float* __restrict__ cdB,
                                             const float2* __restrict__ tw) {
    __shared__ float2 bufA[4096];
    __shared__ float2 bufB[4096];
    int blk = blockIdx.x;
    int bh = blk >> 5, pr = blk & 31;
    int t = threadIdx.x;
    float* colA = Vcol + (size_t)(bh * 64 + pr * 2) * CN;
    float* colB = colA + CN;

    for (int n = t; n < 4096; n += 256) bufA[n] = make_float2(colA[n], colB[n]);
    __syncthreads();

    float2* src = bufA;
    float2* dst = bufB;
    for (int kst = 0; kst < 12; ++kst) {
        int s = 1 << kst;
        int m = 2048 >> kst;
        for (int idx = t; idx < 2048; idx += 256) {
            int p = idx >> kst;
            int q = idx & (s - 1);
            float2 a = src[q + (p << kst)];
            float2 bb = src[q + ((p + m) << kst)];
            float2 wv = tw[p << kst];
            float2 sum = make_float2(a.x + bb.x, a.y + bb.y);
            float2 dif = make_float2(a.x - bb.x, a.y - bb.y);
            float2 wd = make_float2(dif.x * wv.x - dif.y * wv.y, dif.x * wv.y + dif.y * wv.x);
            dst[q + (p << (kst + 1))] = sum;
            dst[q + (p << (kst + 1)) + s] = wd;
        }
        __syncthreads();
        float2* tmp = src; src = dst; dst = tmp;
    }
    const float2* g2 = (const float2*)gateB + (size_t)bh * CFREQ;
    for (int kf = t; kf < 4096; kf += 256) {
        int j = (4096 - kf) & 4095;
        float2 Zk = src[kf], Zj = src[j];
        float2 Av = make_float2(0.5f * (Zk.x + Zj.x), 0.5f * (Zk.y - Zj.y));
        float2 Bv = make_float2(0.5f * (Zk.y + Zj.y), -0.5f * (Zk.x - Zj.x));
        float2 g;
        if (kf <= 2048) g = g2[kf];
        else { float2 gg = g2[4096 - kf]; g = make_float2(gg.x, -gg.y); }
        float2 SA = make_float2(g.x * Av.x - g.y * Av.y, g.x * Av.y + g.y * Av.x);
        float2 SB = make_float2(g.x * Bv.x - g.y * Bv.y, g.x * Bv.y + g.y * Bv.x);
        dst[kf] = make_float2(SA.x - SB.y, SA.y + SB.x);
    }
    __syncthreads();
    { float2* tmp = src; src = dst; dst = tmp; }
    for (int kst = 0; kst < 12; ++kst) {
        int s = 1 << kst;
        int m = 2048 >> kst;
        for (int idx = t; idx < 2048; idx += 256) {
            int p = idx >> kst;
            int q = idx & (s - 1);
            float2 a = src[q + (p << kst)];
            float2 bb = src[q + ((p + m) << kst)];
            float2 wv = tw[p << kst];
            float2 sum = make_float2(a.x + bb.x, a.y + bb.y);
            float2 dif = make_float2(a.x - bb.x, a.y - bb.y);
            float2 wd = make_float2(dif.x * wv.x + dif.y * wv.y, -dif.x * wv.y + dif.y * wv.x);
            dst[q + (p << (kst + 1))] = sum;
            dst[q + (p << (kst + 1)) + s] = wd;
        }
        __syncthreads();
        float2* tmp = src; src = dst; dst = tmp;
    }
    const float scale = 1.0f / 4096.0f;
    const float* ca = caB + (size_t)bh * 2048;
    const float* cd = cdB + (size_t)bh * 2048;
    for (int i = t; i < 2048; i += 256) {
        float2 v0 = src[2 * i], v1 = src[2 * i + 1];
        float a0x = v0.x * scale, a1x = v1.x * scale;
        float a0y = v0.y * scale, a1y = v1.y * scale;
        float A_ = ca[i], D_ = cd[i];
        *(float2*)(colA + 2 * i) = make_float2(A_ * a0x + D_ * a1x, D_ * a0x + A_ * a1x);
        *(float2*)(colB + 2 * i) = make_float2(A_ * a0y + D_ * a1y, D_ * a0y + A_ * a1y);
    }
}

// ---------------- launch ----------------
extern "C" void kernel_launch(void* const* d_in, const int* in_sizes, int n_in,
                              void* d_out, int out_size, void* d_ws, size_t ws_size,
                              hipStream_t stream) {
    const float* x    = (const float*)d_in[0];
    const float* Wq   = (const float*)d_in[1];
    const float* Wv   = (const float*)d_in[2];
    const float* Wo   = (const float*)d_in[3];
    const float* ln_g = (const float*)d_in[4];
    const float* ln_b = (const float*)d_in[5];
    const float* Wgup = (const float*)d_in[6];
    const float* Wgdn = (const float*)d_in[7];
    const float* Wwup = (const float*)d_in[8];
    const float* Wwdn = (const float*)d_in[9];
    float* ws  = (float*)d_ws;
    float* out = (float*)d_out;

    __bf16* xhi  = (__bf16*)(ws + OFF_XHI);
    __bf16* xlo  = (__bf16*)(ws + OFF_XLO);
    __bf16* wvhi = (__bf16*)(ws + OFF_WVHI);
    __bf16* wvlo = (__bf16*)(ws + OFF_WVLO);
    __bf16* wohi = (__bf16*)(ws + OFF_WOHI);
    __bf16* wolo = (__bf16*)(ws + OFF_WOLO);
    __bf16* v2hi = (__bf16*)(ws + OFF_XHI);   // alias: X planes dead after GEMM1
    __bf16* v2lo = (__bf16*)(ws + OFF_XLO);

    hipMemsetAsync(ws + OFF_XSUM, 0, 4096 * sizeof(float), stream);
    k_tw<<<8, 256, 0, stream>>>(ws + OFF_TW);
    k_mean<<<dim3(64, 4), 256, 0, stream>>>(x, ws + OFF_XSUM);
    k_barhidden<<<64, 256, 0, stream>>>(ws + OFF_XSUM, Wq, ln_g, ln_b, Wgup, Wwup,
                                        ws + OFF_HG, ws + OFF_HW);
    k_gategemv<<<dim3(17, 8, 2), 256, 0, stream>>>(Wgdn, Wwdn, ws + OFF_HG, ws + OFF_HW,
                                                   ws + OFF_GATE, ws + OFF_S);
    k_coef<<<dim3(8, 64), 256, 0, stream>>>(ws + OFF_S, ws + OFF_CA, ws + OFF_CD);

    // split X, Wv, Wo into hi/lo bf16 planes
    k_split<<<2048, 256, 0, stream>>>(x, xhi, xlo, CB * CN * CD / 4);
    k_split<<<1024, 256, 0, stream>>>(Wv, wvhi, wvlo, CD * CD / 4);
    k_split<<<1024, 256, 0, stream>>>(Wo, wohi, wolo, CD * CD / 4);

    // GEMM1: Vcol[b*1024+d][n] = x @ Wv.T (transposed store)
    k_mfma_gemm<1><<<dim3(8, 128), 256, 0, stream>>>(xhi, xlo, wvhi, wvlo, ws + OFF_VCOL);

    k_fft<<<2048, 256, 0, stream>>>(ws + OFF_VCOL, ws + OFF_GATE, ws + OFF_CA, ws + OFF_CD,
                                    (const float2*)(ws + OFF_TW));

    // transpose+split v_t for GEMM2
    k_tsplit<<<dim3(128, 32, 4), 256, 0, stream>>>(ws + OFF_VCOL, v2hi, v2lo);

    // GEMM2: out[bn][d'] = v_t @ Wo.T (row-major store)
    k_mfma_gemm<0><<<dim3(8, 128), 256, 0, stream>>>(v2hi, v2lo, wohi, wolo, out);
}

// Round 3
// 474.470 us; speedup vs baseline: 2.0951x; 1.1191x over previous
//
#include <hip/hip_runtime.h>

// ---------------- problem config ----------------
constexpr int CB = 4, CN = 4096, CD = 1024, CH = 16, CDH = 64, CGH = 256, CFREQ = 2049, CBH = 64;

// ---------------- workspace layout (float offsets) ----------------
constexpr size_t OFF_XSUM = 0;                                   // 4096
constexpr size_t OFF_HG   = 4096;
constexpr size_t OFF_HW   = OFF_HG + (size_t)CBH * CGH;
constexpr size_t OFF_GATE = OFF_HW + (size_t)CBH * CGH;
constexpr size_t OFF_S    = OFF_GATE + (size_t)CBH * 2 * CFREQ;
constexpr size_t OFF_CA   = OFF_S + (size_t)CBH * CN;
constexpr size_t OFF_CD   = OFF_CA + (size_t)CBH * (CN / 2);
constexpr size_t OFF_TW   = OFF_CD + (size_t)CBH * (CN / 2);     // 4096 float2 = 8192 floats
constexpr size_t OFF_VCOL = OFF_TW + 8192;                       // fp32 [b][d][n]
constexpr size_t OFF_XHI  = OFF_VCOL + (size_t)CB * CD * CN;     // bf16 planes
constexpr size_t OFF_XLO  = OFF_XHI + (size_t)CB * CN * CD / 2;
constexpr size_t OFF_WVHI = OFF_XLO + (size_t)CB * CN * CD / 2;
constexpr size_t OFF_WVLO = OFF_WVHI + (size_t)CD * CD / 2;
constexpr size_t OFF_WOHI = OFF_WVLO + (size_t)CD * CD / 2;
constexpr size_t OFF_WOLO = OFF_WOHI + (size_t)CD * CD / 2;
// V2 planes alias X planes (X dead after GEMM1)

typedef __bf16 bf16x8 __attribute__((ext_vector_type(8)));
typedef __bf16 bf16x4 __attribute__((ext_vector_type(4)));
typedef float  f32x4  __attribute__((ext_vector_type(4)));

__device__ __forceinline__ float silu_f(float x) { return x / (1.0f + expf(-x)); }

__device__ __forceinline__ void gload16(const void* g, void* l) {
    __builtin_amdgcn_global_load_lds(
        reinterpret_cast<const __attribute__((address_space(1))) unsigned int*>(
            reinterpret_cast<uintptr_t>(g)),
        reinterpret_cast<__attribute__((address_space(3))) unsigned int*>(
            reinterpret_cast<uintptr_t>(l)),
        16, 0, 0);
}

// complex helpers
__device__ __forceinline__ float2 cadd(float2 a, float2 b) { return make_float2(a.x + b.x, a.y + b.y); }
__device__ __forceinline__ float2 csub(float2 a, float2 b) { return make_float2(a.x - b.x, a.y - b.y); }
__device__ __forceinline__ float2 cmul(float2 a, float2 b) { return make_float2(a.x * b.x - a.y * b.y, a.x * b.y + a.y * b.x); }
__device__ __forceinline__ float2 cmulc(float2 a, float2 b) { return make_float2(a.x * b.x + a.y * b.y, a.y * b.x - a.x * b.y); } // a*conj(b)
__device__ __forceinline__ float2 mulni(float2 a) { return make_float2(a.y, -a.x); }  // a * (-i)
__device__ __forceinline__ float2 mulpi(float2 a) { return make_float2(-a.y, a.x); }  // a * (+i)

// LDS bank swizzle (bijective; spreads digit-reversed stride-64 patterns across banks)
__device__ __forceinline__ int fsw(int r) { return r ^ (((r >> 5) ^ (r >> 10)) & 31); }

// base-4 digit reversal of 12-bit index
__device__ __forceinline__ int drev4(int k) {
    return ((k & 3) << 10) | (((k >> 2) & 3) << 8) | (((k >> 4) & 3) << 6)
         | (((k >> 6) & 3) << 4) | (((k >> 8) & 3) << 2) | ((k >> 10) & 3);
}

// ---------------- twiddle table: tw[i] = exp(-2*pi*i*i/4096), i in [0,4096) ----------------
__global__ void k_tw(float* twf) {
    int i = blockIdx.x * 256 + threadIdx.x;
    if (i < 4096) {
        double ang = -2.0 * 3.14159265358979323846 * (double)i / 4096.0;
        twf[2 * i]     = (float)cos(ang);
        twf[2 * i + 1] = (float)sin(ang);
    }
}

// ---------------- column sums of x over N, fused with hi/lo bf16 split ----------------
__global__ __launch_bounds__(256) void k_meansplit(const float* __restrict__ X, float* __restrict__ xsum,
                                                   __bf16* __restrict__ hi, __bf16* __restrict__ lo) {
    int b = blockIdx.y;
    int c = blockIdx.x;
    int t = threadIdx.x;
    const float* base = X + (size_t)b * CN * CD + (size_t)c * 64 * CD + t * 4;
    size_t obase = (size_t)b * CN * CD + (size_t)c * 64 * CD + t * 4;
    float4 acc = make_float4(0.f, 0.f, 0.f, 0.f);
    for (int n = 0; n < 64; ++n) {
        float4 v = *(const float4*)(base + (size_t)n * CD);
        acc.x += v.x; acc.y += v.y; acc.z += v.z; acc.w += v.w;
        __bf16 h0 = (__bf16)v.x, h1 = (__bf16)v.y, h2 = (__bf16)v.z, h3 = (__bf16)v.w;
        bf16x4 hv = {h0, h1, h2, h3};
        bf16x4 lv = {(__bf16)(v.x - (float)h0), (__bf16)(v.y - (float)h1),
                     (__bf16)(v.z - (float)h2), (__bf16)(v.w - (float)h3)};
        *(bf16x4*)&hi[obase + (size_t)n * CD] = hv;
        *(bf16x4*)&lo[obase + (size_t)n * CD] = lv;
    }
    atomicAdd(&xsum[b * CD + 4 * t + 0], acc.x);
    atomicAdd(&xsum[b * CD + 4 * t + 1], acc.y);
    atomicAdd(&xsum[b * CD + 4 * t + 2], acc.z);
    atomicAdd(&xsum[b * CD + 4 * t + 3], acc.w);
}

// ---------------- bar = LN(mean_n q) ; hidden = silu(bar @ Wup.T) ----------------
__global__ __launch_bounds__(256) void k_barhidden(const float* __restrict__ xsum,
                                                   const float* __restrict__ Wq,
                                                   const float* __restrict__ ln_g,
                                                   const float* __restrict__ ln_b,
                                                   const float* __restrict__ Wgup,
                                                   const float* __restrict__ Wwup,
                                                   float* __restrict__ hg, float* __restrict__ hw) {
    int bh = blockIdx.x;
    int b = bh >> 4, h = bh & 15;
    int t = threadIdx.x;
    __shared__ float part[256];
    __shared__ float bar_s[64];
    int dh = t >> 2, seg = t & 3;
    const float* wrow = Wq + (size_t)(h * 64 + dh) * CD + seg * 256;
    const float* xs = xsum + b * CD + seg * 256;
    float acc = 0.f;
    for (int i = 0; i < 256; i += 4) {
        float4 w4 = *(const float4*)(wrow + i);
        float4 x4 = *(const float4*)(xs + i);
        acc += w4.x * x4.x + w4.y * x4.y + w4.z * x4.z + w4.w * x4.w;
    }
    part[t] = acc;
    __syncthreads();
    if (t < 64) {
        float q = (part[4 * t] + part[4 * t + 1] + part[4 * t + 2] + part[4 * t + 3]) * (1.0f / 4096.0f);
        float mu = q;
        for (int o = 32; o >= 1; o >>= 1) mu += __shfl_xor(mu, o, 64);
        mu *= (1.0f / 64.0f);
        float dev = q - mu;
        float vv = dev * dev;
        for (int o = 32; o >= 1; o >>= 1) vv += __shfl_xor(vv, o, 64);
        vv *= (1.0f / 64.0f);
        bar_s[t] = dev / sqrtf(vv + 1e-6f) * ln_g[t] + ln_b[t];
    }
    __syncthreads();
    const float* gup = Wgup + (size_t)t * CDH;
    const float* wup = Wwup + (size_t)t * CDH;
    float ag = 0.f, aw = 0.f;
    for (int i = 0; i < CDH; i += 4) {
        float4 bb = *(const float4*)(&bar_s[i]);
        float4 g4 = *(const float4*)(gup + i);
        float4 w4 = *(const float4*)(wup + i);
        ag += g4.x * bb.x + g4.y * bb.y + g4.z * bb.z + g4.w * bb.w;
        aw += w4.x * bb.x + w4.y * bb.y + w4.z * bb.z + w4.w * bb.w;
    }
    hg[bh * CGH + t] = silu_f(ag);
    hw[bh * CGH + t] = silu_f(aw);
}

// ---------------- gr / s GEMVs ----------------
__global__ __launch_bounds__(256) void k_gategemv(const float* __restrict__ Wgdn,
                                                  const float* __restrict__ Wwdn,
                                                  const float* __restrict__ hg,
                                                  const float* __restrict__ hw,
                                                  float* __restrict__ gate, float* __restrict__ sbuf) {
    int z = blockIdx.z;
    const float* Wd = z ? Wwdn : Wgdn;
    const float* hid = z ? hw : hg;
    float* out = z ? sbuf : gate;
    int Kout = z ? CN : 2 * CFREQ;
    int bh0 = blockIdx.y * 8;
    int t = threadIdx.x;
    int k = blockIdx.x * 256 + t;
    __shared__ float Lh[8][256];
    for (int g = 0; g < 8; ++g) Lh[g][t] = hid[(size_t)(bh0 + g) * CGH + t];
    __syncthreads();
    if (k >= Kout) return;
    float accv[8] = {0.f, 0.f, 0.f, 0.f, 0.f, 0.f, 0.f, 0.f};
    const float* wrow = Wd + (size_t)k * CGH;
    for (int j4 = 0; j4 < 64; ++j4) {
        float4 wv = *(const float4*)(wrow + 4 * j4);
#pragma unroll
        for (int g = 0; g < 8; ++g) {
            accv[g] += wv.x * Lh[g][4 * j4] + wv.y * Lh[g][4 * j4 + 1] +
                       wv.z * Lh[g][4 * j4 + 2] + wv.w * Lh[g][4 * j4 + 3];
        }
    }
    for (int g = 0; g < 8; ++g) out[(size_t)(bh0 + g) * Kout + k] = accv[g];
}

// ---------------- mixing coefficients ----------------
__global__ __launch_bounds__(256) void k_coef(const float* __restrict__ sbuf,
                                              float* __restrict__ ca, float* __restrict__ cd) {
    int bh = blockIdx.y;
    int i = blockIdx.x * 256 + threadIdx.x;
    float s0 = sbuf[(size_t)bh * CN + i];
    float s1 = sbuf[(size_t)bh * CN + 2048 + i];
    ca[(size_t)bh * 2048 + i] = 1.0f + 0.5f * (s0 + s1);
    cd[(size_t)bh * 2048 + i] = 0.5f * (s0 - s1);
}

// ---------------- fp32 -> (hi,lo) bf16 split (weights) ----------------
__global__ __launch_bounds__(256) void k_split(const float* __restrict__ src,
                                               __bf16* __restrict__ hi, __bf16* __restrict__ lo,
                                               int n4) {
    int i = blockIdx.x * 256 + threadIdx.x;
    int stride = gridDim.x * 256;
    for (; i < n4; i += stride) {
        float4 v = ((const float4*)src)[i];
        __bf16 h0 = (__bf16)v.x, h1 = (__bf16)v.y, h2 = (__bf16)v.z, h3 = (__bf16)v.w;
        bf16x4 hv = {h0, h1, h2, h3};
        bf16x4 lv = {(__bf16)(v.x - (float)h0), (__bf16)(v.y - (float)h1),
                     (__bf16)(v.z - (float)h2), (__bf16)(v.w - (float)h3)};
        *(bf16x4*)&hi[4 * (size_t)i] = hv;
        *(bf16x4*)&lo[4 * (size_t)i] = lv;
    }
}

// ---------------- transpose + split: Vcol fp32 [b][d][n] -> V2 planes [b*n][d] ----------------
__global__ __launch_bounds__(256) void k_tsplit(const float* __restrict__ Vcol,
                                                __bf16* __restrict__ hi, __bf16* __restrict__ lo) {
    __shared__ float tile[32][33];
    int bx = blockIdx.x;
    int by = blockIdx.y;
    int b  = blockIdx.z;
    int t = threadIdx.x;
    int d = t >> 3, n4 = (t & 7) * 4;
    const float* src = Vcol + ((size_t)b * CD + by * 32 + d) * CN + bx * 32 + n4;
    float4 v = *(const float4*)src;
    tile[d][n4] = v.x; tile[d][n4 + 1] = v.y; tile[d][n4 + 2] = v.z; tile[d][n4 + 3] = v.w;
    __syncthreads();
    int n = t >> 3, d4 = (t & 7) * 4;
    size_t o = ((size_t)b * CN + bx * 32 + n) * CD + by * 32 + d4;
    float x0 = tile[d4][n], x1 = tile[d4 + 1][n], x2 = tile[d4 + 2][n], x3 = tile[d4 + 3][n];
    __bf16 h0 = (__bf16)x0, h1 = (__bf16)x1, h2 = (__bf16)x2, h3 = (__bf16)x3;
    bf16x4 hv = {h0, h1, h2, h3};
    bf16x4 lv = {(__bf16)(x0 - (float)h0), (__bf16)(x1 - (float)h1),
                 (__bf16)(x2 - (float)h2), (__bf16)(x3 - (float)h3)};
    *(bf16x4*)&hi[o] = hv;
    *(bf16x4*)&lo[o] = lv;
}

// ---------------- split-bf16 MFMA GEMM (unchanged from round 2) ----------------
template <int TRANS>
__global__ __launch_bounds__(256) void k_mfma_gemm(const __bf16* __restrict__ Ahi,
                                                   const __bf16* __restrict__ Alo,
                                                   const __bf16* __restrict__ Bhi,
                                                   const __bf16* __restrict__ Blo,
                                                   float* __restrict__ C) {
    __shared__ __align__(16) __bf16 lds[4][128 * 32];
    int t = threadIdx.x;
    int l = t & 63, w = t >> 6;
    int m0 = blockIdx.y * 128;
    int n0 = blockIdx.x * 128;
    int wm = w >> 1, wn = w & 1;

    const __bf16* gsrc = (w == 0) ? Ahi : (w == 1) ? Alo : (w == 2) ? Bhi : Blo;
    int gr0 = (w < 2) ? m0 : n0;
    unsigned o[8];
#pragma unroll
    for (int i = 0; i < 8; ++i) {
        int row = i * 16 + (l >> 2);
        unsigned slot = (unsigned)((l & 3) ^ ((row >> 2) & 3));
        o[i] = (unsigned)(gr0 + row) * 1024u + slot * 8u;
    }
    __bf16* ldsw = &lds[w][0];

    f32x4 acc[4][4];
#pragma unroll
    for (int m = 0; m < 4; ++m)
#pragma unroll
        for (int n = 0; n < 4; ++n) acc[m][n] = (f32x4){0.f, 0.f, 0.f, 0.f};

    for (int k0 = 0; k0 < 1024; k0 += 32) {
#pragma unroll
        for (int i = 0; i < 8; ++i)
            gload16(gsrc + ((size_t)o[i] + k0), ldsw + i * 512);
        __syncthreads();

        bf16x8 ah[4], al[4], bh[4], bl[4];
#pragma unroll
        for (int m = 0; m < 4; ++m) {
            int row = wm * 64 + m * 16 + (l & 15);
            int sl = (l >> 4) ^ ((row >> 2) & 3);
            ah[m] = *(const bf16x8*)&lds[0][row * 32 + sl * 8];
            al[m] = *(const bf16x8*)&lds[1][row * 32 + sl * 8];
        }
#pragma unroll
        for (int n = 0; n < 4; ++n) {
            int row = wn * 64 + n * 16 + (l & 15);
            int sl = (l >> 4) ^ ((row >> 2) & 3);
            bh[n] = *(const bf16x8*)&lds[2][row * 32 + sl * 8];
            bl[n] = *(const bf16x8*)&lds[3][row * 32 + sl * 8];
        }
#pragma unroll
        for (int m = 0; m < 4; ++m)
#pragma unroll
            for (int n = 0; n < 4; ++n) {
                acc[m][n] = __builtin_amdgcn_mfma_f32_16x16x32_bf16(ah[m], bh[n], acc[m][n], 0, 0, 0);
                acc[m][n] = __builtin_amdgcn_mfma_f32_16x16x32_bf16(ah[m], bl[n], acc[m][n], 0, 0, 0);
                acc[m][n] = __builtin_amdgcn_mfma_f32_16x16x32_bf16(al[m], bh[n], acc[m][n], 0, 0, 0);
            }
        __syncthreads();
    }

    if (TRANS) {
        int b = m0 >> 12;
        int tokb = (m0 & 4095) + wm * 64;
#pragma unroll
        for (int m = 0; m < 4; ++m)
#pragma unroll
            for (int n = 0; n < 4; ++n) {
                int dcol = n0 + wn * 64 + n * 16 + (l & 15);
                int tok = tokb + m * 16 + ((l >> 4) << 2);
                *(f32x4*)&C[((size_t)(b * CD + dcol)) * CN + tok] = acc[m][n];
            }
    } else {
#pragma unroll
        for (int m = 0; m < 4; ++m)
#pragma unroll
            for (int n = 0; n < 4; ++n) {
                int r0 = m0 + wm * 64 + m * 16 + ((l >> 4) << 2);
                int cc = n0 + wn * 64 + n * 16 + (l & 15);
#pragma unroll
                for (int q = 0; q < 4; ++q) C[(size_t)(r0 + q) * CD + cc] = acc[m][n][q];
            }
    }
}

// ---------------- FFT chain: in-place radix-4, 32 KiB LDS, swizzled banks ----------------
// fwd DIF (natural -> base4-digit-reversed), hermitian gate in digit-reversed order,
// inv DIT (digit-reversed -> natural), then 1/N + 2x2 adjacent mix.
__global__ __launch_bounds__(256) void k_fft(float* __restrict__ Vcol,
                                             const float* __restrict__ gateB,
                                             const float* __restrict__ caB,
                                             const float* __restrict__ cdB,
                                             const float2* __restrict__ tw) {
    __shared__ float2 buf[4096];
    int blk = blockIdx.x;
    int bh = blk >> 5, pr = blk & 31;
    int t = threadIdx.x;
    float* colA = Vcol + (size_t)(bh * 64 + pr * 2) * CN;
    float* colB = colA + CN;

    for (int n = t; n < 4096; n += 256) buf[fsw(n)] = make_float2(colA[n], colB[n]);
    __syncthreads();

    // forward: DIF radix-4, M = 1024,256,64,16,4,1 ; twiddle W_(4M)^(j*p) = tw[j*p*1024/M]
#pragma unroll 1
    for (int M = 1024; M >= 1; M >>= 2) {
        int tstep = 1024 / M;
        for (int idx = t; idx < 1024; idx += 256) {
            int j = idx & (M - 1);
            int i0 = ((idx & ~(M - 1)) << 2) + j;
            float2 a0 = buf[fsw(i0)];
            float2 a1 = buf[fsw(i0 + M)];
            float2 a2 = buf[fsw(i0 + 2 * M)];
            float2 a3 = buf[fsw(i0 + 3 * M)];
            float2 t0 = cadd(a0, a2), t1 = csub(a0, a2);
            float2 t2 = cadd(a1, a3), t3 = csub(a1, a3);
            float2 w1 = tw[j * tstep], w2 = tw[2 * j * tstep], w3 = tw[3 * j * tstep];
            buf[fsw(i0)]         = cadd(t0, t2);
            buf[fsw(i0 + M)]     = cmul(cadd(t1, mulni(t3)), w1);   // t1 - i*t3
            buf[fsw(i0 + 2 * M)] = cmul(csub(t0, t2), w2);
            buf[fsw(i0 + 3 * M)] = cmul(cadd(t1, mulpi(t3)), w3);   // t1 + i*t3
        }
        __syncthreads();
    }

    // hermitian unpack + gate + repack, digit-reversed storage; thread owns pair {k, 4096-k}
    const float2* g2 = (const float2*)gateB + (size_t)bh * CFREQ;
    for (int k = t; k <= 2048; k += 256) {
        int r  = drev4(k);
        int r2 = drev4((4096 - k) & 4095);
        float2 Zk = buf[fsw(r)];
        float2 Zj = buf[fsw(r2)];
        float2 Av = make_float2(0.5f * (Zk.x + Zj.x), 0.5f * (Zk.y - Zj.y));
        float2 Bv = make_float2(0.5f * (Zk.y + Zj.y), -0.5f * (Zk.x - Zj.x));
        float2 g = g2[k];
        float2 SA = cmul(g, Av);
        float2 SB = cmul(g, Bv);
        buf[fsw(r)] = make_float2(SA.x - SB.y, SA.y + SB.x);
        if (r2 != r) buf[fsw(r2)] = make_float2(SA.x + SB.y, SB.x - SA.y);  // conj(SA)+i*conj(SB)
    }
    __syncthreads();

    // inverse: DIT radix-4, M = 1,4,...,1024 ; twiddle conj(tw[j*p*1024/M])
#pragma unroll 1
    for (int M = 1; M <= 1024; M <<= 2) {
        int tstep = 1024 / M;
        for (int idx = t; idx < 1024; idx += 256) {
            int j = idx & (M - 1);
            int i0 = ((idx & ~(M - 1)) << 2) + j;
            float2 a0 = buf[fsw(i0)];
            float2 a1 = cmulc(buf[fsw(i0 + M)], tw[j * tstep]);
            float2 a2 = cmulc(buf[fsw(i0 + 2 * M)], tw[2 * j * tstep]);
            float2 a3 = cmulc(buf[fsw(i0 + 3 * M)], tw[3 * j * tstep]);
            float2 t0 = cadd(a0, a2), t1 = csub(a0, a2);
            float2 t2 = cadd(a1, a3), t3 = csub(a1, a3);
            buf[fsw(i0)]         = cadd(t0, t2);
            buf[fsw(i0 + M)]     = cadd(t1, mulpi(t3));
            buf[fsw(i0 + 2 * M)] = csub(t0, t2);
            buf[fsw(i0 + 3 * M)] = csub(t1, mulpi(t3));
        }
        __syncthreads();
    }

    // epilogue: 1/N + 2x2 adjacent mix, store back
    const float scale = 1.0f / 4096.0f;
    const float* ca = caB + (size_t)bh * 2048;
    const float* cd = cdB + (size_t)bh * 2048;
    for (int i = t; i < 2048; i += 256) {
        float2 v0 = buf[fsw(2 * i)], v1 = buf[fsw(2 * i + 1)];
        float a0x = v0.x * scale, a1x = v1.x * scale;
        float a0y = v0.y * scale, a1y = v1.y * scale;
        float A_ = ca[i], D_ = cd[i];
        *(float2*)(colA + 2 * i) = make_float2(A_ * a0x + D_ * a1x, D_ * a0x + A_ * a1x);
        *(float2*)(colB + 2 * i) = make_float2(A_ * a0y + D_ * a1y, D_ * a0y + A_ * a1y);
    }
}

// ---------------- launch ----------------
extern "C" void kernel_launch(void* const* d_in, const int* in_sizes, int n_in,
                              void* d_out, int out_size, void* d_ws, size_t ws_size,
                              hipStream_t stream) {
    const float* x    = (const float*)d_in[0];
    const float* Wq   = (const float*)d_in[1];
    const float* Wv   = (const float*)d_in[2];
    const float* Wo   = (const float*)d_in[3];
    const float* ln_g = (const float*)d_in[4];
    const float* ln_b = (const float*)d_in[5];
    const float* Wgup = (const float*)d_in[6];
    const float* Wgdn = (const float*)d_in[7];
    const float* Wwup = (const float*)d_in[8];
    const float* Wwdn = (const float*)d_in[9];
    float* ws  = (float*)d_ws;
    float* out = (float*)d_out;

    __bf16* xhi  = (__bf16*)(ws + OFF_XHI);
    __bf16* xlo  = (__bf16*)(ws + OFF_XLO);
    __bf16* wvhi = (__bf16*)(ws + OFF_WVHI);
    __bf16* wvlo = (__bf16*)(ws + OFF_WVLO);
    __bf16* wohi = (__bf16*)(ws + OFF_WOHI);
    __bf16* wolo = (__bf16*)(ws + OFF_WOLO);
    __bf16* v2hi = (__bf16*)(ws + OFF_XHI);   // alias: X planes dead after GEMM1
    __bf16* v2lo = (__bf16*)(ws + OFF_XLO);

    hipMemsetAsync(ws + OFF_XSUM, 0, 4096 * sizeof(float), stream);
    k_tw<<<16, 256, 0, stream>>>(ws + OFF_TW);
    k_meansplit<<<dim3(64, 4), 256, 0, stream>>>(x, ws + OFF_XSUM, xhi, xlo);
    k_barhidden<<<64, 256, 0, stream>>>(ws + OFF_XSUM, Wq, ln_g, ln_b, Wgup, Wwup,
                                        ws + OFF_HG, ws + OFF_HW);
    k_gategemv<<<dim3(17, 8, 2), 256, 0, stream>>>(Wgdn, Wwdn, ws + OFF_HG, ws + OFF_HW,
                                                   ws + OFF_GATE, ws + OFF_S);
    k_coef<<<dim3(8, 64), 256, 0, stream>>>(ws + OFF_S, ws + OFF_CA, ws + OFF_CD);

    k_split<<<1024, 256, 0, stream>>>(Wv, wvhi, wvlo, CD * CD / 4);
    k_split<<<1024, 256, 0, stream>>>(Wo, wohi, wolo, CD * CD / 4);

    // GEMM1: Vcol[b*1024+d][n] = x @ Wv.T (transposed store)
    k_mfma_gemm<1><<<dim3(8, 128), 256, 0, stream>>>(xhi, xlo, wvhi, wvlo, ws + OFF_VCOL);

    k_fft<<<2048, 256, 0, stream>>>(ws + OFF_VCOL, ws + OFF_GATE, ws + OFF_CA, ws + OFF_CD,
                                    (const float2*)(ws + OFF_TW));

    // transpose+split v_t for GEMM2
    k_tsplit<<<dim3(128, 32, 4), 256, 0, stream>>>(ws + OFF_VCOL, v2hi, v2lo);

    // GEMM2: out[bn][d'] = v_t @ Wo.T (row-major store)
    k_mfma_gemm<0><<<dim3(8, 128), 256, 0, stream>>>(v2hi, v2lo, wohi, wolo, out);
}

// Round 4
// 450.659 us; speedup vs baseline: 2.2058x; 1.0528x over previous
//
#include <hip/hip_runtime.h>

// ---------------- problem config ----------------
constexpr int CB = 4, CN = 4096, CD = 1024, CH = 16, CDH = 64, CGH = 256, CFREQ = 2049, CBH = 64;

// ---------------- workspace layout (float offsets) ----------------
constexpr size_t OFF_XSUM = 0;                                   // 4096
constexpr size_t OFF_HG   = 4096;
constexpr size_t OFF_HW   = OFF_HG + (size_t)CBH * CGH;
constexpr size_t OFF_GATE = OFF_HW + (size_t)CBH * CGH;
constexpr size_t OFF_S    = OFF_GATE + (size_t)CBH * 2 * CFREQ;
constexpr size_t OFF_CA   = OFF_S + (size_t)CBH * CN;
constexpr size_t OFF_CD   = OFF_CA + (size_t)CBH * (CN / 2);
constexpr size_t OFF_TW   = OFF_CD + (size_t)CBH * (CN / 2);     // 4096 float2 = 8192 floats
constexpr size_t OFF_VCOL = OFF_TW + 8192;                       // fp32 [b][d][n]
constexpr size_t OFF_XHI  = OFF_VCOL + (size_t)CB * CD * CN;     // bf16 planes
constexpr size_t OFF_XLO  = OFF_XHI + (size_t)CB * CN * CD / 2;
constexpr size_t OFF_WVHI = OFF_XLO + (size_t)CB * CN * CD / 2;
constexpr size_t OFF_WVLO = OFF_WVHI + (size_t)CD * CD / 2;
constexpr size_t OFF_WOHI = OFF_WVLO + (size_t)CD * CD / 2;
constexpr size_t OFF_WOLO = OFF_WOHI + (size_t)CD * CD / 2;
// V2 planes alias X planes (X dead after GEMM1)

typedef __bf16 bf16x8 __attribute__((ext_vector_type(8)));
typedef __bf16 bf16x4 __attribute__((ext_vector_type(4)));
typedef float  f32x4  __attribute__((ext_vector_type(4)));

__device__ __forceinline__ float silu_f(float x) { return x / (1.0f + expf(-x)); }

__device__ __forceinline__ void gload16(const void* g, void* l) {
    __builtin_amdgcn_global_load_lds(
        reinterpret_cast<const __attribute__((address_space(1))) unsigned int*>(
            reinterpret_cast<uintptr_t>(g)),
        reinterpret_cast<__attribute__((address_space(3))) unsigned int*>(
            reinterpret_cast<uintptr_t>(l)),
        16, 0, 0);
}

// complex helpers
__device__ __forceinline__ float2 cadd(float2 a, float2 b) { return make_float2(a.x + b.x, a.y + b.y); }
__device__ __forceinline__ float2 csub(float2 a, float2 b) { return make_float2(a.x - b.x, a.y - b.y); }
__device__ __forceinline__ float2 cmul(float2 a, float2 b) { return make_float2(a.x * b.x - a.y * b.y, a.x * b.y + a.y * b.x); }
__device__ __forceinline__ float2 cmulc(float2 a, float2 b) { return make_float2(a.x * b.x + a.y * b.y, a.y * b.x - a.x * b.y); } // a*conj(b)
__device__ __forceinline__ float2 mulni(float2 a) { return make_float2(a.y, -a.x); }  // a * (-i)
__device__ __forceinline__ float2 mulpi(float2 a) { return make_float2(-a.y, a.x); }  // a * (+i)

// LDS bank swizzle (bijective)
__device__ __forceinline__ int fsw(int r) { return r ^ (((r >> 5) ^ (r >> 10)) & 31); }

// base-4 digit reversal of 12-bit index
__device__ __forceinline__ int drev4(int k) {
    return ((k & 3) << 10) | (((k >> 2) & 3) << 8) | (((k >> 4) & 3) << 6)
         | (((k >> 6) & 3) << 4) | (((k >> 8) & 3) << 2) | ((k >> 10) & 3);
}

// ---------------- twiddle table ----------------
__global__ void k_tw(float* twf) {
    int i = blockIdx.x * 256 + threadIdx.x;
    if (i < 4096) {
        double ang = -2.0 * 3.14159265358979323846 * (double)i / 4096.0;
        twf[2 * i]     = (float)cos(ang);
        twf[2 * i + 1] = (float)sin(ang);
    }
}

// ---------------- column sums of x over N, fused with hi/lo bf16 split ----------------
__global__ __launch_bounds__(256) void k_meansplit(const float* __restrict__ X, float* __restrict__ xsum,
                                                   __bf16* __restrict__ hi, __bf16* __restrict__ lo) {
    int b = blockIdx.y;
    int c = blockIdx.x;
    int t = threadIdx.x;
    const float* base = X + (size_t)b * CN * CD + (size_t)c * 64 * CD + t * 4;
    size_t obase = (size_t)b * CN * CD + (size_t)c * 64 * CD + t * 4;
    float4 acc = make_float4(0.f, 0.f, 0.f, 0.f);
    for (int n = 0; n < 64; ++n) {
        float4 v = *(const float4*)(base + (size_t)n * CD);
        acc.x += v.x; acc.y += v.y; acc.z += v.z; acc.w += v.w;
        __bf16 h0 = (__bf16)v.x, h1 = (__bf16)v.y, h2 = (__bf16)v.z, h3 = (__bf16)v.w;
        bf16x4 hv = {h0, h1, h2, h3};
        bf16x4 lv = {(__bf16)(v.x - (float)h0), (__bf16)(v.y - (float)h1),
                     (__bf16)(v.z - (float)h2), (__bf16)(v.w - (float)h3)};
        *(bf16x4*)&hi[obase + (size_t)n * CD] = hv;
        *(bf16x4*)&lo[obase + (size_t)n * CD] = lv;
    }
    atomicAdd(&xsum[b * CD + 4 * t + 0], acc.x);
    atomicAdd(&xsum[b * CD + 4 * t + 1], acc.y);
    atomicAdd(&xsum[b * CD + 4 * t + 2], acc.z);
    atomicAdd(&xsum[b * CD + 4 * t + 3], acc.w);
}

// ---------------- bar = LN(mean_n q) ; hidden = silu(bar @ Wup.T) ----------------
__global__ __launch_bounds__(256) void k_barhidden(const float* __restrict__ xsum,
                                                   const float* __restrict__ Wq,
                                                   const float* __restrict__ ln_g,
                                                   const float* __restrict__ ln_b,
                                                   const float* __restrict__ Wgup,
                                                   const float* __restrict__ Wwup,
                                                   float* __restrict__ hg, float* __restrict__ hw) {
    int bh = blockIdx.x;
    int b = bh >> 4, h = bh & 15;
    int t = threadIdx.x;
    __shared__ float part[256];
    __shared__ float bar_s[64];
    int dh = t >> 2, seg = t & 3;
    const float* wrow = Wq + (size_t)(h * 64 + dh) * CD + seg * 256;
    const float* xs = xsum + b * CD + seg * 256;
    float acc = 0.f;
    for (int i = 0; i < 256; i += 4) {
        float4 w4 = *(const float4*)(wrow + i);
        float4 x4 = *(const float4*)(xs + i);
        acc += w4.x * x4.x + w4.y * x4.y + w4.z * x4.z + w4.w * x4.w;
    }
    part[t] = acc;
    __syncthreads();
    if (t < 64) {
        float q = (part[4 * t] + part[4 * t + 1] + part[4 * t + 2] + part[4 * t + 3]) * (1.0f / 4096.0f);
        float mu = q;
        for (int o = 32; o >= 1; o >>= 1) mu += __shfl_xor(mu, o, 64);
        mu *= (1.0f / 64.0f);
        float dev = q - mu;
        float vv = dev * dev;
        for (int o = 32; o >= 1; o >>= 1) vv += __shfl_xor(vv, o, 64);
        vv *= (1.0f / 64.0f);
        bar_s[t] = dev / sqrtf(vv + 1e-6f) * ln_g[t] + ln_b[t];
    }
    __syncthreads();
    const float* gup = Wgup + (size_t)t * CDH;
    const float* wup = Wwup + (size_t)t * CDH;
    float ag = 0.f, aw = 0.f;
    for (int i = 0; i < CDH; i += 4) {
        float4 bb = *(const float4*)(&bar_s[i]);
        float4 g4 = *(const float4*)(gup + i);
        float4 w4 = *(const float4*)(wup + i);
        ag += g4.x * bb.x + g4.y * bb.y + g4.z * bb.z + g4.w * bb.w;
        aw += w4.x * bb.x + w4.y * bb.y + w4.z * bb.z + w4.w * bb.w;
    }
    hg[bh * CGH + t] = silu_f(ag);
    hw[bh * CGH + t] = silu_f(aw);
}

// ---------------- gr / s GEMVs ----------------
__global__ __launch_bounds__(256) void k_gategemv(const float* __restrict__ Wgdn,
                                                  const float* __restrict__ Wwdn,
                                                  const float* __restrict__ hg,
                                                  const float* __restrict__ hw,
                                                  float* __restrict__ gate, float* __restrict__ sbuf) {
    int z = blockIdx.z;
    const float* Wd = z ? Wwdn : Wgdn;
    const float* hid = z ? hw : hg;
    float* out = z ? sbuf : gate;
    int Kout = z ? CN : 2 * CFREQ;
    int bh0 = blockIdx.y * 8;
    int t = threadIdx.x;
    int k = blockIdx.x * 256 + t;
    __shared__ float Lh[8][256];
    for (int g = 0; g < 8; ++g) Lh[g][t] = hid[(size_t)(bh0 + g) * CGH + t];
    __syncthreads();
    if (k >= Kout) return;
    float accv[8] = {0.f, 0.f, 0.f, 0.f, 0.f, 0.f, 0.f, 0.f};
    const float* wrow = Wd + (size_t)k * CGH;
    for (int j4 = 0; j4 < 64; ++j4) {
        float4 wv = *(const float4*)(wrow + 4 * j4);
#pragma unroll
        for (int g = 0; g < 8; ++g) {
            accv[g] += wv.x * Lh[g][4 * j4] + wv.y * Lh[g][4 * j4 + 1] +
                       wv.z * Lh[g][4 * j4 + 2] + wv.w * Lh[g][4 * j4 + 3];
        }
    }
    for (int g = 0; g < 8; ++g) out[(size_t)(bh0 + g) * Kout + k] = accv[g];
}

// ---------------- mixing coefficients ----------------
__global__ __launch_bounds__(256) void k_coef(const float* __restrict__ sbuf,
                                              float* __restrict__ ca, float* __restrict__ cd) {
    int bh = blockIdx.y;
    int i = blockIdx.x * 256 + threadIdx.x;
    float s0 = sbuf[(size_t)bh * CN + i];
    float s1 = sbuf[(size_t)bh * CN + 2048 + i];
    ca[(size_t)bh * 2048 + i] = 1.0f + 0.5f * (s0 + s1);
    cd[(size_t)bh * 2048 + i] = 0.5f * (s0 - s1);
}

// ---------------- fp32 -> (hi,lo) bf16 split (weights) ----------------
__global__ __launch_bounds__(256) void k_split(const float* __restrict__ src,
                                               __bf16* __restrict__ hi, __bf16* __restrict__ lo,
                                               int n4) {
    int i = blockIdx.x * 256 + threadIdx.x;
    int stride = gridDim.x * 256;
    for (; i < n4; i += stride) {
        float4 v = ((const float4*)src)[i];
        __bf16 h0 = (__bf16)v.x, h1 = (__bf16)v.y, h2 = (__bf16)v.z, h3 = (__bf16)v.w;
        bf16x4 hv = {h0, h1, h2, h3};
        bf16x4 lv = {(__bf16)(v.x - (float)h0), (__bf16)(v.y - (float)h1),
                     (__bf16)(v.z - (float)h2), (__bf16)(v.w - (float)h3)};
        *(bf16x4*)&hi[4 * (size_t)i] = hv;
        *(bf16x4*)&lo[4 * (size_t)i] = lv;
    }
}

// ---------------- transpose + split: Vcol fp32 [b][d][n] -> V2 planes [b*n][d] ----------------
__global__ __launch_bounds__(256) void k_tsplit(const float* __restrict__ Vcol,
                                                __bf16* __restrict__ hi, __bf16* __restrict__ lo) {
    __shared__ float tile[32][33];
    int bx = blockIdx.x;
    int by = blockIdx.y;
    int b  = blockIdx.z;
    int t = threadIdx.x;
    int d = t >> 3, n4 = (t & 7) * 4;
    const float* src = Vcol + ((size_t)b * CD + by * 32 + d) * CN + bx * 32 + n4;
    float4 v = *(const float4*)src;
    tile[d][n4] = v.x; tile[d][n4 + 1] = v.y; tile[d][n4 + 2] = v.z; tile[d][n4 + 3] = v.w;
    __syncthreads();
    int n = t >> 3, d4 = (t & 7) * 4;
    size_t o = ((size_t)b * CN + bx * 32 + n) * CD + by * 32 + d4;
    float x0 = tile[d4][n], x1 = tile[d4 + 1][n], x2 = tile[d4 + 2][n], x3 = tile[d4 + 3][n];
    __bf16 h0 = (__bf16)x0, h1 = (__bf16)x1, h2 = (__bf16)x2, h3 = (__bf16)x3;
    bf16x4 hv = {h0, h1, h2, h3};
    bf16x4 lv = {(__bf16)(x0 - (float)h0), (__bf16)(x1 - (float)h1),
                 (__bf16)(x2 - (float)h2), (__bf16)(x3 - (float)h3)};
    *(bf16x4*)&hi[o] = hv;
    *(bf16x4*)&lo[o] = lv;
}

// ---------------- split-bf16 MFMA GEMM with XCD-grouped block remap ----------------
// hw id -> (xcd = hw&7, slot = hw>>3); m-tile = xcd*16 + slot/8, n-tile = slot&7.
// All 8 n-blocks sharing an A m-tile land on the SAME XCD and run concurrently
// (all 1024 blocks co-resident at 4 blocks/CU) -> A k-slices hit in that XCD's L2.
template <int TRANS>
__global__ __launch_bounds__(256) void k_mfma_gemm(const __bf16* __restrict__ Ahi,
                                                   const __bf16* __restrict__ Alo,
                                                   const __bf16* __restrict__ Bhi,
                                                   const __bf16* __restrict__ Blo,
                                                   float* __restrict__ C) {
    __shared__ __align__(16) __bf16 lds[4][128 * 32];
    int t = threadIdx.x;
    int l = t & 63, w = t >> 6;
    int hw = blockIdx.x + (blockIdx.y << 3);
    int xcd = hw & 7, slot = hw >> 3;
    int m0 = (xcd * 16 + (slot >> 3)) * 128;
    int n0 = (slot & 7) * 128;
    int wm = w >> 1, wn = w & 1;

    const __bf16* gsrc = (w == 0) ? Ahi : (w == 1) ? Alo : (w == 2) ? Bhi : Blo;
    int gr0 = (w < 2) ? m0 : n0;
    unsigned o[8];
#pragma unroll
    for (int i = 0; i < 8; ++i) {
        int row = i * 16 + (l >> 2);
        unsigned slotq = (unsigned)((l & 3) ^ ((row >> 2) & 3));
        o[i] = (unsigned)(gr0 + row) * 1024u + slotq * 8u;
    }
    __bf16* ldsw = &lds[w][0];

    f32x4 acc[4][4];
#pragma unroll
    for (int m = 0; m < 4; ++m)
#pragma unroll
        for (int n = 0; n < 4; ++n) acc[m][n] = (f32x4){0.f, 0.f, 0.f, 0.f};

    for (int k0 = 0; k0 < 1024; k0 += 32) {
#pragma unroll
        for (int i = 0; i < 8; ++i)
            gload16(gsrc + ((size_t)o[i] + k0), ldsw + i * 512);
        __syncthreads();

        bf16x8 ah[4], al[4], bh[4], bl[4];
#pragma unroll
        for (int m = 0; m < 4; ++m) {
            int row = wm * 64 + m * 16 + (l & 15);
            int sl = (l >> 4) ^ ((row >> 2) & 3);
            ah[m] = *(const bf16x8*)&lds[0][row * 32 + sl * 8];
            al[m] = *(const bf16x8*)&lds[1][row * 32 + sl * 8];
        }
#pragma unroll
        for (int n = 0; n < 4; ++n) {
            int row = wn * 64 + n * 16 + (l & 15);
            int sl = (l >> 4) ^ ((row >> 2) & 3);
            bh[n] = *(const bf16x8*)&lds[2][row * 32 + sl * 8];
            bl[n] = *(const bf16x8*)&lds[3][row * 32 + sl * 8];
        }
#pragma unroll
        for (int m = 0; m < 4; ++m)
#pragma unroll
            for (int n = 0; n < 4; ++n) {
                acc[m][n] = __builtin_amdgcn_mfma_f32_16x16x32_bf16(ah[m], bh[n], acc[m][n], 0, 0, 0);
                acc[m][n] = __builtin_amdgcn_mfma_f32_16x16x32_bf16(ah[m], bl[n], acc[m][n], 0, 0, 0);
                acc[m][n] = __builtin_amdgcn_mfma_f32_16x16x32_bf16(al[m], bh[n], acc[m][n], 0, 0, 0);
            }
        __syncthreads();
    }

    if (TRANS) {
        int b = m0 >> 12;
        int tokb = (m0 & 4095) + wm * 64;
#pragma unroll
        for (int m = 0; m < 4; ++m)
#pragma unroll
            for (int n = 0; n < 4; ++n) {
                int dcol = n0 + wn * 64 + n * 16 + (l & 15);
                int tok = tokb + m * 16 + ((l >> 4) << 2);
                *(f32x4*)&C[((size_t)(b * CD + dcol)) * CN + tok] = acc[m][n];
            }
    } else {
#pragma unroll
        for (int m = 0; m < 4; ++m)
#pragma unroll
            for (int n = 0; n < 4; ++n) {
                int r0 = m0 + wm * 64 + m * 16 + ((l >> 4) << 2);
                int cc = n0 + wn * 64 + n * 16 + (l & 15);
#pragma unroll
                for (int q = 0; q < 4; ++q) C[(size_t)(r0 + q) * CD + cc] = acc[m][n][q];
            }
    }
}

// ---------------- FFT chain: in-place radix-4, 32 KiB LDS, swizzled banks ----------------
__global__ __launch_bounds__(256) void k_fft(float* __restrict__ Vcol,
                                             const float* __restrict__ gateB,
                                             const float* __restrict__ caB,
                                             const float* __restrict__ cdB,
                                             const float2* __restrict__ tw) {
    __shared__ float2 buf[4096];
    int blk = blockIdx.x;
    int bh = blk >> 5, pr = blk & 31;
    int t = threadIdx.x;
    float* colA = Vcol + (size_t)(bh * 64 + pr * 2) * CN;
    float* colB = colA + CN;

    for (int n = t; n < 4096; n += 256) buf[fsw(n)] = make_float2(colA[n], colB[n]);
    __syncthreads();

#pragma unroll 1
    for (int M = 1024; M >= 1; M >>= 2) {
        int tstep = 1024 / M;
        for (int idx = t; idx < 1024; idx += 256) {
            int j = idx & (M - 1);
            int i0 = ((idx & ~(M - 1)) << 2) + j;
            float2 a0 = buf[fsw(i0)];
            float2 a1 = buf[fsw(i0 + M)];
            float2 a2 = buf[fsw(i0 + 2 * M)];
            float2 a3 = buf[fsw(i0 + 3 * M)];
            float2 t0 = cadd(a0, a2), t1 = csub(a0, a2);
            float2 t2 = cadd(a1, a3), t3 = csub(a1, a3);
            float2 w1 = tw[j * tstep], w2 = tw[2 * j * tstep], w3 = tw[3 * j * tstep];
            buf[fsw(i0)]         = cadd(t0, t2);
            buf[fsw(i0 + M)]     = cmul(cadd(t1, mulni(t3)), w1);
            buf[fsw(i0 + 2 * M)] = cmul(csub(t0, t2), w2);
            buf[fsw(i0 + 3 * M)] = cmul(cadd(t1, mulpi(t3)), w3);
        }
        __syncthreads();
    }

    const float2* g2 = (const float2*)gateB + (size_t)bh * CFREQ;
    for (int k = t; k <= 2048; k += 256) {
        int r  = drev4(k);
        int r2 = drev4((4096 - k) & 4095);
        float2 Zk = buf[fsw(r)];
        float2 Zj = buf[fsw(r2)];
        float2 Av = make_float2(0.5f * (Zk.x + Zj.x), 0.5f * (Zk.y - Zj.y));
        float2 Bv = make_float2(0.5f * (Zk.y + Zj.y), -0.5f * (Zk.x - Zj.x));
        float2 g = g2[k];
        float2 SA = cmul(g, Av);
        float2 SB = cmul(g, Bv);
        buf[fsw(r)] = make_float2(SA.x - SB.y, SA.y + SB.x);
        if (r2 != r) buf[fsw(r2)] = make_float2(SA.x + SB.y, SB.x - SA.y);
    }
    __syncthreads();

#pragma unroll 1
    for (int M = 1; M <= 1024; M <<= 2) {
        int tstep = 1024 / M;
        for (int idx = t; idx < 1024; idx += 256) {
            int j = idx & (M - 1);
            int i0 = ((idx & ~(M - 1)) << 2) + j;
            float2 a0 = buf[fsw(i0)];
            float2 a1 = cmulc(buf[fsw(i0 + M)], tw[j * tstep]);
            float2 a2 = cmulc(buf[fsw(i0 + 2 * M)], tw[2 * j * tstep]);
            float2 a3 = cmulc(buf[fsw(i0 + 3 * M)], tw[3 * j * tstep]);
            float2 t0 = cadd(a0, a2), t1 = csub(a0, a2);
            float2 t2 = cadd(a1, a3), t3 = csub(a1, a3);
            buf[fsw(i0)]         = cadd(t0, t2);
            buf[fsw(i0 + M)]     = cadd(t1, mulpi(t3));
            buf[fsw(i0 + 2 * M)] = csub(t0, t2);
            buf[fsw(i0 + 3 * M)] = csub(t1, mulpi(t3));
        }
        __syncthreads();
    }

    const float scale = 1.0f / 4096.0f;
    const float* ca = caB + (size_t)bh * 2048;
    const float* cd = cdB + (size_t)bh * 2048;
    for (int i = t; i < 2048; i += 256) {
        float2 v0 = buf[fsw(2 * i)], v1 = buf[fsw(2 * i + 1)];
        float a0x = v0.x * scale, a1x = v1.x * scale;
        float a0y = v0.y * scale, a1y = v1.y * scale;
        float A_ = ca[i], D_ = cd[i];
        *(float2*)(colA + 2 * i) = make_float2(A_ * a0x + D_ * a1x, D_ * a0x + A_ * a1x);
        *(float2*)(colB + 2 * i) = make_float2(A_ * a0y + D_ * a1y, D_ * a0y + A_ * a1y);
    }
}

// ---------------- launch ----------------
extern "C" void kernel_launch(void* const* d_in, const int* in_sizes, int n_in,
                              void* d_out, int out_size, void* d_ws, size_t ws_size,
                              hipStream_t stream) {
    const float* x    = (const float*)d_in[0];
    const float* Wq   = (const float*)d_in[1];
    const float* Wv   = (const float*)d_in[2];
    const float* Wo   = (const float*)d_in[3];
    const float* ln_g = (const float*)d_in[4];
    const float* ln_b = (const float*)d_in[5];
    const float* Wgup = (const float*)d_in[6];
    const float* Wgdn = (const float*)d_in[7];
    const float* Wwup = (const float*)d_in[8];
    const float* Wwdn = (const float*)d_in[9];
    float* ws  = (float*)d_ws;
    float* out = (float*)d_out;

    __bf16* xhi  = (__bf16*)(ws + OFF_XHI);
    __bf16* xlo  = (__bf16*)(ws + OFF_XLO);
    __bf16* wvhi = (__bf16*)(ws + OFF_WVHI);
    __bf16* wvlo = (__bf16*)(ws + OFF_WVLO);
    __bf16* wohi = (__bf16*)(ws + OFF_WOHI);
    __bf16* wolo = (__bf16*)(ws + OFF_WOLO);
    __bf16* v2hi = (__bf16*)(ws + OFF_XHI);   // alias: X planes dead after GEMM1
    __bf16* v2lo = (__bf16*)(ws + OFF_XLO);

    hipMemsetAsync(ws + OFF_XSUM, 0, 4096 * sizeof(float), stream);
    k_tw<<<16, 256, 0, stream>>>(ws + OFF_TW);
    k_meansplit<<<dim3(64, 4), 256, 0, stream>>>(x, ws + OFF_XSUM, xhi, xlo);
    k_barhidden<<<64, 256, 0, stream>>>(ws + OFF_XSUM, Wq, ln_g, ln_b, Wgup, Wwup,
                                        ws + OFF_HG, ws + OFF_HW);
    k_gategemv<<<dim3(17, 8, 2), 256, 0, stream>>>(Wgdn, Wwdn, ws + OFF_HG, ws + OFF_HW,
                                                   ws + OFF_GATE, ws + OFF_S);
    k_coef<<<dim3(8, 64), 256, 0, stream>>>(ws + OFF_S, ws + OFF_CA, ws + OFF_CD);

    k_split<<<1024, 256, 0, stream>>>(Wv, wvhi, wvlo, CD * CD / 4);
    k_split<<<1024, 256, 0, stream>>>(Wo, wohi, wolo, CD * CD / 4);

    // GEMM1: Vcol[b*1024+d][n] = x @ Wv.T (transposed store)
    k_mfma_gemm<1><<<dim3(8, 128), 256, 0, stream>>>(xhi, xlo, wvhi, wvlo, ws + OFF_VCOL);

    k_fft<<<2048, 256, 0, stream>>>(ws + OFF_VCOL, ws + OFF_GATE, ws + OFF_CA, ws + OFF_CD,
                                    (const float2*)(ws + OFF_TW));

    // transpose+split v_t for GEMM2
    k_tsplit<<<dim3(128, 32, 4), 256, 0, stream>>>(ws + OFF_VCOL, v2hi, v2lo);

    // GEMM2: out[bn][d'] = v_t @ Wo.T (row-major store)
    k_mfma_gemm<0><<<dim3(8, 128), 256, 0, stream>>>(v2hi, v2lo, wohi, wolo, out);
}

// Round 5
// 418.090 us; speedup vs baseline: 2.3776x; 1.0779x over previous
//
#include <hip/hip_runtime.h>

// ---------------- problem config ----------------
constexpr int CB = 4, CN = 4096, CD = 1024, CH = 16, CDH = 64, CGH = 256, CFREQ = 2049, CBH = 64;

// ---------------- workspace layout (float offsets) ----------------
constexpr size_t OFF_XSUM = 0;                                   // 4096
constexpr size_t OFF_HG   = 4096;
constexpr size_t OFF_HW   = OFF_HG + (size_t)CBH * CGH;
constexpr size_t OFF_GATE = OFF_HW + (size_t)CBH * CGH;
constexpr size_t OFF_S    = OFF_GATE + (size_t)CBH * 2 * CFREQ;
constexpr size_t OFF_CA   = OFF_S + (size_t)CBH * CN;
constexpr size_t OFF_CD   = OFF_CA + (size_t)CBH * (CN / 2);
constexpr size_t OFF_TW   = OFF_CD + (size_t)CBH * (CN / 2);     // 4096 float2 = 8192 floats
constexpr size_t OFF_VCOL = OFF_TW + 8192;                       // fp32 [b][d][n]
constexpr size_t OFF_XHI  = OFF_VCOL + (size_t)CB * CD * CN;     // bf16 planes
constexpr size_t OFF_XLO  = OFF_XHI + (size_t)CB * CN * CD / 2;
constexpr size_t OFF_WVHI = OFF_XLO + (size_t)CB * CN * CD / 2;
constexpr size_t OFF_WVLO = OFF_WVHI + (size_t)CD * CD / 2;
constexpr size_t OFF_WOHI = OFF_WVLO + (size_t)CD * CD / 2;
constexpr size_t OFF_WOLO = OFF_WOHI + (size_t)CD * CD / 2;
// V2 planes alias X planes (X dead after GEMM1)

typedef __bf16 bf16x8 __attribute__((ext_vector_type(8)));
typedef __bf16 bf16x4 __attribute__((ext_vector_type(4)));
typedef float  f32x4  __attribute__((ext_vector_type(4)));

__device__ __forceinline__ float silu_f(float x) { return x / (1.0f + expf(-x)); }

__device__ __forceinline__ void gload16(const void* g, void* l) {
    __builtin_amdgcn_global_load_lds(
        reinterpret_cast<const __attribute__((address_space(1))) unsigned int*>(
            reinterpret_cast<uintptr_t>(g)),
        reinterpret_cast<__attribute__((address_space(3))) unsigned int*>(
            reinterpret_cast<uintptr_t>(l)),
        16, 0, 0);
}

// complex helpers
__device__ __forceinline__ float2 cadd(float2 a, float2 b) { return make_float2(a.x + b.x, a.y + b.y); }
__device__ __forceinline__ float2 csub(float2 a, float2 b) { return make_float2(a.x - b.x, a.y - b.y); }
__device__ __forceinline__ float2 cmul(float2 a, float2 b) { return make_float2(a.x * b.x - a.y * b.y, a.x * b.y + a.y * b.x); }
__device__ __forceinline__ float2 cmulc(float2 a, float2 b) { return make_float2(a.x * b.x + a.y * b.y, a.y * b.x - a.x * b.y); } // a*conj(b)
__device__ __forceinline__ float2 mulni(float2 a) { return make_float2(a.y, -a.x); }  // a * (-i)
__device__ __forceinline__ float2 mulpi(float2 a) { return make_float2(-a.y, a.x); }  // a * (+i)

// LDS bank swizzle (bijective)
__device__ __forceinline__ int fsw(int r) { return r ^ (((r >> 5) ^ (r >> 10)) & 31); }

// base-4 digit reversal of 12-bit index
__device__ __forceinline__ int drev4(int k) {
    return ((k & 3) << 10) | (((k >> 2) & 3) << 8) | (((k >> 4) & 3) << 6)
         | (((k >> 6) & 3) << 4) | (((k >> 8) & 3) << 2) | ((k >> 10) & 3);
}

// ---------------- twiddle table ----------------
__global__ void k_tw(float* twf) {
    int i = blockIdx.x * 256 + threadIdx.x;
    if (i < 4096) {
        double ang = -2.0 * 3.14159265358979323846 * (double)i / 4096.0;
        twf[2 * i]     = (float)cos(ang);
        twf[2 * i + 1] = (float)sin(ang);
    }
}

// ---------------- column sums of x over N, fused with hi/lo bf16 split ----------------
__global__ __launch_bounds__(256) void k_meansplit(const float* __restrict__ X, float* __restrict__ xsum,
                                                   __bf16* __restrict__ hi, __bf16* __restrict__ lo) {
    int b = blockIdx.y;
    int c = blockIdx.x;
    int t = threadIdx.x;
    const float* base = X + (size_t)b * CN * CD + (size_t)c * 64 * CD + t * 4;
    size_t obase = (size_t)b * CN * CD + (size_t)c * 64 * CD + t * 4;
    float4 acc = make_float4(0.f, 0.f, 0.f, 0.f);
    for (int n = 0; n < 64; ++n) {
        float4 v = *(const float4*)(base + (size_t)n * CD);
        acc.x += v.x; acc.y += v.y; acc.z += v.z; acc.w += v.w;
        __bf16 h0 = (__bf16)v.x, h1 = (__bf16)v.y, h2 = (__bf16)v.z, h3 = (__bf16)v.w;
        bf16x4 hv = {h0, h1, h2, h3};
        bf16x4 lv = {(__bf16)(v.x - (float)h0), (__bf16)(v.y - (float)h1),
                     (__bf16)(v.z - (float)h2), (__bf16)(v.w - (float)h3)};
        *(bf16x4*)&hi[obase + (size_t)n * CD] = hv;
        *(bf16x4*)&lo[obase + (size_t)n * CD] = lv;
    }
    atomicAdd(&xsum[b * CD + 4 * t + 0], acc.x);
    atomicAdd(&xsum[b * CD + 4 * t + 1], acc.y);
    atomicAdd(&xsum[b * CD + 4 * t + 2], acc.z);
    atomicAdd(&xsum[b * CD + 4 * t + 3], acc.w);
}

// ---------------- bar = LN(mean_n q) ; hidden = silu(bar @ Wup.T) ----------------
__global__ __launch_bounds__(256) void k_barhidden(const float* __restrict__ xsum,
                                                   const float* __restrict__ Wq,
                                                   const float* __restrict__ ln_g,
                                                   const float* __restrict__ ln_b,
                                                   const float* __restrict__ Wgup,
                                                   const float* __restrict__ Wwup,
                                                   float* __restrict__ hg, float* __restrict__ hw) {
    int bh = blockIdx.x;
    int b = bh >> 4, h = bh & 15;
    int t = threadIdx.x;
    __shared__ float part[256];
    __shared__ float bar_s[64];
    int dh = t >> 2, seg = t & 3;
    const float* wrow = Wq + (size_t)(h * 64 + dh) * CD + seg * 256;
    const float* xs = xsum + b * CD + seg * 256;
    float acc = 0.f;
    for (int i = 0; i < 256; i += 4) {
        float4 w4 = *(const float4*)(wrow + i);
        float4 x4 = *(const float4*)(xs + i);
        acc += w4.x * x4.x + w4.y * x4.y + w4.z * x4.z + w4.w * x4.w;
    }
    part[t] = acc;
    __syncthreads();
    if (t < 64) {
        float q = (part[4 * t] + part[4 * t + 1] + part[4 * t + 2] + part[4 * t + 3]) * (1.0f / 4096.0f);
        float mu = q;
        for (int o = 32; o >= 1; o >>= 1) mu += __shfl_xor(mu, o, 64);
        mu *= (1.0f / 64.0f);
        float dev = q - mu;
        float vv = dev * dev;
        for (int o = 32; o >= 1; o >>= 1) vv += __shfl_xor(vv, o, 64);
        vv *= (1.0f / 64.0f);
        bar_s[t] = dev / sqrtf(vv + 1e-6f) * ln_g[t] + ln_b[t];
    }
    __syncthreads();
    const float* gup = Wgup + (size_t)t * CDH;
    const float* wup = Wwup + (size_t)t * CDH;
    float ag = 0.f, aw = 0.f;
    for (int i = 0; i < CDH; i += 4) {
        float4 bb = *(const float4*)(&bar_s[i]);
        float4 g4 = *(const float4*)(gup + i);
        float4 w4 = *(const float4*)(wup + i);
        ag += g4.x * bb.x + g4.y * bb.y + g4.z * bb.z + g4.w * bb.w;
        aw += w4.x * bb.x + w4.y * bb.y + w4.z * bb.z + w4.w * bb.w;
    }
    hg[bh * CGH + t] = silu_f(ag);
    hw[bh * CGH + t] = silu_f(aw);
}

// ---------------- gr / s GEMVs ----------------
__global__ __launch_bounds__(256) void k_gategemv(const float* __restrict__ Wgdn,
                                                  const float* __restrict__ Wwdn,
                                                  const float* __restrict__ hg,
                                                  const float* __restrict__ hw,
                                                  float* __restrict__ gate, float* __restrict__ sbuf) {
    int z = blockIdx.z;
    const float* Wd = z ? Wwdn : Wgdn;
    const float* hid = z ? hw : hg;
    float* out = z ? sbuf : gate;
    int Kout = z ? CN : 2 * CFREQ;
    int bh0 = blockIdx.y * 8;
    int t = threadIdx.x;
    int k = blockIdx.x * 256 + t;
    __shared__ float Lh[8][256];
    for (int g = 0; g < 8; ++g) Lh[g][t] = hid[(size_t)(bh0 + g) * CGH + t];
    __syncthreads();
    if (k >= Kout) return;
    float accv[8] = {0.f, 0.f, 0.f, 0.f, 0.f, 0.f, 0.f, 0.f};
    const float* wrow = Wd + (size_t)k * CGH;
    for (int j4 = 0; j4 < 64; ++j4) {
        float4 wv = *(const float4*)(wrow + 4 * j4);
#pragma unroll
        for (int g = 0; g < 8; ++g) {
            accv[g] += wv.x * Lh[g][4 * j4] + wv.y * Lh[g][4 * j4 + 1] +
                       wv.z * Lh[g][4 * j4 + 2] + wv.w * Lh[g][4 * j4 + 3];
        }
    }
    for (int g = 0; g < 8; ++g) out[(size_t)(bh0 + g) * Kout + k] = accv[g];
}

// ---------------- mixing coefficients ----------------
__global__ __launch_bounds__(256) void k_coef(const float* __restrict__ sbuf,
                                              float* __restrict__ ca, float* __restrict__ cd) {
    int bh = blockIdx.y;
    int i = blockIdx.x * 256 + threadIdx.x;
    float s0 = sbuf[(size_t)bh * CN + i];
    float s1 = sbuf[(size_t)bh * CN + 2048 + i];
    ca[(size_t)bh * 2048 + i] = 1.0f + 0.5f * (s0 + s1);
    cd[(size_t)bh * 2048 + i] = 0.5f * (s0 - s1);
}

// ---------------- fp32 -> (hi,lo) bf16 split (weights) ----------------
__global__ __launch_bounds__(256) void k_split(const float* __restrict__ src,
                                               __bf16* __restrict__ hi, __bf16* __restrict__ lo,
                                               int n4) {
    int i = blockIdx.x * 256 + threadIdx.x;
    int stride = gridDim.x * 256;
    for (; i < n4; i += stride) {
        float4 v = ((const float4*)src)[i];
        __bf16 h0 = (__bf16)v.x, h1 = (__bf16)v.y, h2 = (__bf16)v.z, h3 = (__bf16)v.w;
        bf16x4 hv = {h0, h1, h2, h3};
        bf16x4 lv = {(__bf16)(v.x - (float)h0), (__bf16)(v.y - (float)h1),
                     (__bf16)(v.z - (float)h2), (__bf16)(v.w - (float)h3)};
        *(bf16x4*)&hi[4 * (size_t)i] = hv;
        *(bf16x4*)&lo[4 * (size_t)i] = lv;
    }
}

// ---------------- transpose + split: Vcol fp32 [b][d][n] -> V2 planes [b*n][d] ----------------
__global__ __launch_bounds__(256) void k_tsplit(const float* __restrict__ Vcol,
                                                __bf16* __restrict__ hi, __bf16* __restrict__ lo) {
    __shared__ float tile[32][33];
    int bx = blockIdx.x;
    int by = blockIdx.y;
    int b  = blockIdx.z;
    int t = threadIdx.x;
    int d = t >> 3, n4 = (t & 7) * 4;
    const float* src = Vcol + ((size_t)b * CD + by * 32 + d) * CN + bx * 32 + n4;
    float4 v = *(const float4*)src;
    tile[d][n4] = v.x; tile[d][n4 + 1] = v.y; tile[d][n4 + 2] = v.z; tile[d][n4 + 3] = v.w;
    __syncthreads();
    int n = t >> 3, d4 = (t & 7) * 4;
    size_t o = ((size_t)b * CN + bx * 32 + n) * CD + by * 32 + d4;
    float x0 = tile[d4][n], x1 = tile[d4 + 1][n], x2 = tile[d4 + 2][n], x3 = tile[d4 + 3][n];
    __bf16 h0 = (__bf16)x0, h1 = (__bf16)x1, h2 = (__bf16)x2, h3 = (__bf16)x3;
    bf16x4 hv = {h0, h1, h2, h3};
    bf16x4 lv = {(__bf16)(x0 - (float)h0), (__bf16)(x1 - (float)h1),
                 (__bf16)(x2 - (float)h2), (__bf16)(x3 - (float)h3)};
    *(bf16x4*)&hi[o] = hv;
    *(bf16x4*)&lo[o] = lv;
}

// ---------------- split-bf16 MFMA GEMM: 2-phase double-buffered (catalog T3-minimum) ----------------
// XCD-grouped remap kept (FETCH ideal). Per K-step: issue STAGE(next buf) first,
// then ds_read+48 MFMA on current buf, then ONE __syncthreads() (implicit vmcnt0
// drain waits on loads that had the whole MFMA phase in flight). One barrier/K-step.
template <int TRANS>
__global__ __launch_bounds__(256) void k_mfma_gemm(const __bf16* __restrict__ Ahi,
                                                   const __bf16* __restrict__ Alo,
                                                   const __bf16* __restrict__ Bhi,
                                                   const __bf16* __restrict__ Blo,
                                                   float* __restrict__ C) {
    __shared__ __align__(16) __bf16 lds[2][4][128 * 32];   // dbuf x {Ahi,Alo,Bhi,Blo}
    int t = threadIdx.x;
    int l = t & 63, w = t >> 6;
    int hw = blockIdx.x + (blockIdx.y << 3);
    int xcd = hw & 7, slot = hw >> 3;
    int m0 = (xcd * 16 + (slot >> 3)) * 128;
    int n0 = (slot & 7) * 128;
    int wm = w >> 1, wn = w & 1;

    // staging: wave w stages plane w (8 chunks of 16 rows x 32 cols).
    // global source pre-swizzled so LDS dest stays linear (m173 pattern).
    const __bf16* gsrc = (w == 0) ? Ahi : (w == 1) ? Alo : (w == 2) ? Bhi : Blo;
    int gr0 = (w < 2) ? m0 : n0;
    unsigned o[8];
#pragma unroll
    for (int i = 0; i < 8; ++i) {
        int row = i * 16 + (l >> 2);
        unsigned slotq = (unsigned)((l & 3) ^ ((row >> 2) & 3));
        o[i] = (unsigned)(gr0 + row) * 1024u + slotq * 8u;
    }

    f32x4 acc[4][4];
#pragma unroll
    for (int m = 0; m < 4; ++m)
#pragma unroll
        for (int n = 0; n < 4; ++n) acc[m][n] = (f32x4){0.f, 0.f, 0.f, 0.f};

    // prologue: stage k0=0 into buf 0
#pragma unroll
    for (int i = 0; i < 8; ++i)
        gload16(gsrc + (size_t)o[i], &lds[0][w][i * 512]);
    __syncthreads();

    int cur = 0;
#pragma unroll 2
    for (int k0 = 0; k0 < 1024; k0 += 32) {
        // issue next tile's async loads into the other buffer (overlaps with MFMA below)
        if (k0 + 32 < 1024) {
#pragma unroll
            for (int i = 0; i < 8; ++i)
                gload16(gsrc + ((size_t)o[i] + k0 + 32), &lds[cur ^ 1][w][i * 512]);
        }

        bf16x8 ah[4], al[4], bh[4], bl[4];
#pragma unroll
        for (int m = 0; m < 4; ++m) {
            int row = wm * 64 + m * 16 + (l & 15);
            int sl = (l >> 4) ^ ((row >> 2) & 3);
            ah[m] = *(const bf16x8*)&lds[cur][0][row * 32 + sl * 8];
            al[m] = *(const bf16x8*)&lds[cur][1][row * 32 + sl * 8];
        }
#pragma unroll
        for (int n = 0; n < 4; ++n) {
            int row = wn * 64 + n * 16 + (l & 15);
            int sl = (l >> 4) ^ ((row >> 2) & 3);
            bh[n] = *(const bf16x8*)&lds[cur][2][row * 32 + sl * 8];
            bl[n] = *(const bf16x8*)&lds[cur][3][row * 32 + sl * 8];
        }
#pragma unroll
        for (int m = 0; m < 4; ++m)
#pragma unroll
            for (int n = 0; n < 4; ++n) {
                acc[m][n] = __builtin_amdgcn_mfma_f32_16x16x32_bf16(ah[m], bh[n], acc[m][n], 0, 0, 0);
                acc[m][n] = __builtin_amdgcn_mfma_f32_16x16x32_bf16(ah[m], bl[n], acc[m][n], 0, 0, 0);
                acc[m][n] = __builtin_amdgcn_mfma_f32_16x16x32_bf16(al[m], bh[n], acc[m][n], 0, 0, 0);
            }
        __syncthreads();   // drains vmcnt(0): next buffer complete; all waves done reading cur
        cur ^= 1;
    }

    if (TRANS) {
        int b = m0 >> 12;
        int tokb = (m0 & 4095) + wm * 64;
#pragma unroll
        for (int m = 0; m < 4; ++m)
#pragma unroll
            for (int n = 0; n < 4; ++n) {
                int dcol = n0 + wn * 64 + n * 16 + (l & 15);
                int tok = tokb + m * 16 + ((l >> 4) << 2);
                *(f32x4*)&C[((size_t)(b * CD + dcol)) * CN + tok] = acc[m][n];
            }
    } else {
#pragma unroll
        for (int m = 0; m < 4; ++m)
#pragma unroll
            for (int n = 0; n < 4; ++n) {
                int r0 = m0 + wm * 64 + m * 16 + ((l >> 4) << 2);
                int cc = n0 + wn * 64 + n * 16 + (l & 15);
#pragma unroll
                for (int q = 0; q < 4; ++q) C[(size_t)(r0 + q) * CD + cc] = acc[m][n][q];
            }
    }
}

// ---------------- FFT chain: in-place radix-4, 32 KiB LDS, swizzled banks ----------------
__global__ __launch_bounds__(256) void k_fft(float* __restrict__ Vcol,
                                             const float* __restrict__ gateB,
                                             const float* __restrict__ caB,
                                             const float* __restrict__ cdB,
                                             const float2* __restrict__ tw) {
    __shared__ float2 buf[4096];
    int blk = blockIdx.x;
    int bh = blk >> 5, pr = blk & 31;
    int t = threadIdx.x;
    float* colA = Vcol + (size_t)(bh * 64 + pr * 2) * CN;
    float* colB = colA + CN;

    for (int n = t; n < 4096; n += 256) buf[fsw(n)] = make_float2(colA[n], colB[n]);
    __syncthreads();

#pragma unroll 1
    for (int M = 1024; M >= 1; M >>= 2) {
        int tstep = 1024 / M;
        for (int idx = t; idx < 1024; idx += 256) {
            int j = idx & (M - 1);
            int i0 = ((idx & ~(M - 1)) << 2) + j;
            float2 a0 = buf[fsw(i0)];
            float2 a1 = buf[fsw(i0 + M)];
            float2 a2 = buf[fsw(i0 + 2 * M)];
            float2 a3 = buf[fsw(i0 + 3 * M)];
            float2 t0 = cadd(a0, a2), t1 = csub(a0, a2);
            float2 t2 = cadd(a1, a3), t3 = csub(a1, a3);
            float2 w1 = tw[j * tstep], w2 = tw[2 * j * tstep], w3 = tw[3 * j * tstep];
            buf[fsw(i0)]         = cadd(t0, t2);
            buf[fsw(i0 + M)]     = cmul(cadd(t1, mulni(t3)), w1);
            buf[fsw(i0 + 2 * M)] = cmul(csub(t0, t2), w2);
            buf[fsw(i0 + 3 * M)] = cmul(cadd(t1, mulpi(t3)), w3);
        }
        __syncthreads();
    }

    const float2* g2 = (const float2*)gateB + (size_t)bh * CFREQ;
    for (int k = t; k <= 2048; k += 256) {
        int r  = drev4(k);
        int r2 = drev4((4096 - k) & 4095);
        float2 Zk = buf[fsw(r)];
        float2 Zj = buf[fsw(r2)];
        float2 Av = make_float2(0.5f * (Zk.x + Zj.x), 0.5f * (Zk.y - Zj.y));
        float2 Bv = make_float2(0.5f * (Zk.y + Zj.y), -0.5f * (Zk.x - Zj.x));
        float2 g = g2[k];
        float2 SA = cmul(g, Av);
        float2 SB = cmul(g, Bv);
        buf[fsw(r)] = make_float2(SA.x - SB.y, SA.y + SB.x);
        if (r2 != r) buf[fsw(r2)] = make_float2(SA.x + SB.y, SB.x - SA.y);
    }
    __syncthreads();

#pragma unroll 1
    for (int M = 1; M <= 1024; M <<= 2) {
        int tstep = 1024 / M;
        for (int idx = t; idx < 1024; idx += 256) {
            int j = idx & (M - 1);
            int i0 = ((idx & ~(M - 1)) << 2) + j;
            float2 a0 = buf[fsw(i0)];
            float2 a1 = cmulc(buf[fsw(i0 + M)], tw[j * tstep]);
            float2 a2 = cmulc(buf[fsw(i0 + 2 * M)], tw[2 * j * tstep]);
            float2 a3 = cmulc(buf[fsw(i0 + 3 * M)], tw[3 * j * tstep]);
            float2 t0 = cadd(a0, a2), t1 = csub(a0, a2);
            float2 t2 = cadd(a1, a3), t3 = csub(a1, a3);
            buf[fsw(i0)]         = cadd(t0, t2);
            buf[fsw(i0 + M)]     = cadd(t1, mulpi(t3));
            buf[fsw(i0 + 2 * M)] = csub(t0, t2);
            buf[fsw(i0 + 3 * M)] = csub(t1, mulpi(t3));
        }
        __syncthreads();
    }

    const float scale = 1.0f / 4096.0f;
    const float* ca = caB + (size_t)bh * 2048;
    const float* cd = cdB + (size_t)bh * 2048;
    for (int i = t; i < 2048; i += 256) {
        float2 v0 = buf[fsw(2 * i)], v1 = buf[fsw(2 * i + 1)];
        float a0x = v0.x * scale, a1x = v1.x * scale;
        float a0y = v0.y * scale, a1y = v1.y * scale;
        float A_ = ca[i], D_ = cd[i];
        *(float2*)(colA + 2 * i) = make_float2(A_ * a0x + D_ * a1x, D_ * a0x + A_ * a1x);
        *(float2*)(colB + 2 * i) = make_float2(A_ * a0y + D_ * a1y, D_ * a0y + A_ * a1y);
    }
}

// ---------------- launch ----------------
extern "C" void kernel_launch(void* const* d_in, const int* in_sizes, int n_in,
                              void* d_out, int out_size, void* d_ws, size_t ws_size,
                              hipStream_t stream) {
    const float* x    = (const float*)d_in[0];
    const float* Wq   = (const float*)d_in[1];
    const float* Wv   = (const float*)d_in[2];
    const float* Wo   = (const float*)d_in[3];
    const float* ln_g = (const float*)d_in[4];
    const float* ln_b = (const float*)d_in[5];
    const float* Wgup = (const float*)d_in[6];
    const float* Wgdn = (const float*)d_in[7];
    const float* Wwup = (const float*)d_in[8];
    const float* Wwdn = (const float*)d_in[9];
    float* ws  = (float*)d_ws;
    float* out = (float*)d_out;

    __bf16* xhi  = (__bf16*)(ws + OFF_XHI);
    __bf16* xlo  = (__bf16*)(ws + OFF_XLO);
    __bf16* wvhi = (__bf16*)(ws + OFF_WVHI);
    __bf16* wvlo = (__bf16*)(ws + OFF_WVLO);
    __bf16* wohi = (__bf16*)(ws + OFF_WOHI);
    __bf16* wolo = (__bf16*)(ws + OFF_WOLO);
    __bf16* v2hi = (__bf16*)(ws + OFF_XHI);   // alias: X planes dead after GEMM1
    __bf16* v2lo = (__bf16*)(ws + OFF_XLO);

    hipMemsetAsync(ws + OFF_XSUM, 0, 4096 * sizeof(float), stream);
    k_tw<<<16, 256, 0, stream>>>(ws + OFF_TW);
    k_meansplit<<<dim3(64, 4), 256, 0, stream>>>(x, ws + OFF_XSUM, xhi, xlo);
    k_barhidden<<<64, 256, 0, stream>>>(ws + OFF_XSUM, Wq, ln_g, ln_b, Wgup, Wwup,
                                        ws + OFF_HG, ws + OFF_HW);
    k_gategemv<<<dim3(17, 8, 2), 256, 0, stream>>>(Wgdn, Wwdn, ws + OFF_HG, ws + OFF_HW,
                                                   ws + OFF_GATE, ws + OFF_S);
    k_coef<<<dim3(8, 64), 256, 0, stream>>>(ws + OFF_S, ws + OFF_CA, ws + OFF_CD);

    k_split<<<1024, 256, 0, stream>>>(Wv, wvhi, wvlo, CD * CD / 4);
    k_split<<<1024, 256, 0, stream>>>(Wo, wohi, wolo, CD * CD / 4);

    // GEMM1: Vcol[b*1024+d][n] = x @ Wv.T (transposed store)
    k_mfma_gemm<1><<<dim3(8, 128), 256, 0, stream>>>(xhi, xlo, wvhi, wvlo, ws + OFF_VCOL);

    k_fft<<<2048, 256, 0, stream>>>(ws + OFF_VCOL, ws + OFF_GATE, ws + OFF_CA, ws + OFF_CD,
                                    (const float2*)(ws + OFF_TW));

    // transpose+split v_t for GEMM2
    k_tsplit<<<dim3(128, 32, 4), 256, 0, stream>>>(ws + OFF_VCOL, v2hi, v2lo);

    // GEMM2: out[bn][d'] = v_t @ Wo.T (row-major store)
    k_mfma_gemm<0><<<dim3(8, 128), 256, 0, stream>>>(v2hi, v2lo, wohi, wolo, out);
}